// Round 1
// baseline (11389.923 us; speedup 1.0000x reference)
//
#include <hip/hip_runtime.h>
#include <hip/hip_bf16.h>

typedef __bf16 bf16;
typedef __bf16 bf16x8 __attribute__((ext_vector_type(8)));
typedef float floatx4 __attribute__((ext_vector_type(4)));
typedef float floatx16 __attribute__((ext_vector_type(16)));

#define TSEQ 512

__device__ __forceinline__ float sigm(float x){ return 1.0f/(1.0f + __expf(-x)); }
__device__ __forceinline__ float tanh_fast(float x){
    float e = __expf(2.0f*x);
    return 1.0f - 2.0f/(e + 1.0f);   // correct limits at +-inf
}

// fp32 -> bf16 converter
__global__ __launch_bounds__(256, 4)
void f2b_kernel(const float* __restrict__ in, bf16* __restrict__ out, int n)
{
    int i = blockIdx.x*256 + threadIdx.x;
    if (i < n) out[i] = (bf16)in[i];
}

// ---------------------------------------------------------------------------
// Pack Whh (1024 x 256 fp32) into MFMA-16x16x32 B-frag-major bf16 layout:
// Wp[ntile 0..63][kstep 0..7][lane 0..63][e 0..7], value =
//   Whh[gatecol = ntile*16 + (lane&15)][k = kstep*32 + (lane>>4)*8 + e]
// One thread per frag-lane (32768 threads), 8 contiguous fp32 reads each.
// ---------------------------------------------------------------------------
__global__ __launch_bounds__(256, 4)
void pack_whh(const float* __restrict__ whh, bf16* __restrict__ wp)
{
    int idx = blockIdx.x*256 + threadIdx.x;
    if (idx >= 32768) return;
    int lane = idx & 63, ks = (idx >> 6) & 7, nt = idx >> 9;
    int row = nt*16 + (lane & 15);
    int k0  = ks*32 + (lane >> 4)*8;
    const float* src = whh + (size_t)row*256 + k0;
    bf16x8 v;
    #pragma unroll
    for (int e = 0; e < 8; e++) v[e] = (bf16)src[e];
    ((bf16x8*)wp)[idx] = v;
}

// ---------------------------------------------------------------------------
// xg = x @ Wih^T + b for a 128-step chunk, both directions (blockIdx.z).
// Output layout: xg[dir][seq 0..63][sloc 0..127][1024] fp32, where sloc is
// the STEP index (fwd: t = chunk*128+sloc, bwd: t = 511-(chunk*128+sloc)).
// 64x64 tile GEMM, 32x32x16 MFMA (same scheme as attention GEMMs below).
// ---------------------------------------------------------------------------
template<int DIN, bool XF32>
__global__ __launch_bounds__(256, 2)
void xg_gemm(const void* __restrict__ xin,
             const bf16* __restrict__ wbf, const bf16* __restrict__ wbb,
             const float* __restrict__ bf_, const float* __restrict__ bb_,
             float* __restrict__ xg, int chunk)
{
    __shared__ char smem[64*144*2];
    const int tid = threadIdx.x;
    const int wave = tid >> 6, lane = tid & 63;
    const int mi = wave & 1, ni = wave >> 1;
    const int l31 = lane & 31, lh = lane >> 5;
    char* At = smem;
    char* Bt = smem + 64*144;

    const int d   = blockIdx.z;
    const int seq = blockIdx.x >> 1;
    const int sl0 = (blockIdx.x & 1) * 64;
    const int n0  = blockIdx.y * 64;
    const bf16*  wb   = d ? wbb : wbf;
    const float* bias = d ? bb_ : bf_;
    const int t0  = d ? (TSEQ-1 - (chunk*128 + sl0)) : (chunk*128 + sl0);
    const int stp = d ? -1 : 1;

    floatx16 acc;
    #pragma unroll
    for (int r = 0; r < 16; r++) acc[r] = 0.0f;

    for (int kc = 0; kc < DIN; kc += 64) {
        __syncthreads();
        for (int c = tid; c < 1024; c += 256) {
            const int which = c >> 9, idx = c & 511;
            const int row = idx >> 3, k8 = idx & 7;
            if (which == 0) {
                const long trow = (long)t0 + (long)row*stp;
                if constexpr (XF32) {
                    const float* src = (const float*)xin
                        + ((long)seq*TSEQ + trow)*DIN + kc + k8*8;
                    const float4 lo = *(const float4*)src;
                    const float4 hi = *(const float4*)(src+4);
                    bf16 tmp[8] = {(bf16)lo.x,(bf16)lo.y,(bf16)lo.z,(bf16)lo.w,
                                   (bf16)hi.x,(bf16)hi.y,(bf16)hi.z,(bf16)hi.w};
                    *(uint4*)(At + row*144 + k8*16) = *(uint4*)tmp;
                } else {
                    const bf16* src = (const bf16*)xin
                        + ((long)seq*TSEQ + trow)*DIN + kc + k8*8;
                    *(uint4*)(At + row*144 + k8*16) = *(const uint4*)src;
                }
            } else {
                *(uint4*)(Bt + row*144 + k8*16) =
                    *(const uint4*)(wb + (size_t)(n0+row)*DIN + kc + k8*8);
            }
        }
        __syncthreads();
        #pragma unroll
        for (int ks = 0; ks < 4; ks++) {
            bf16x8 a = *(const bf16x8*)(At + (mi*32 + l31)*144 + ks*32 + lh*16);
            bf16x8 b = *(const bf16x8*)(Bt + (ni*32 + l31)*144 + ks*32 + lh*16);
            acc = __builtin_amdgcn_mfma_f32_32x32x16_bf16(a, b, acc, 0, 0, 0);
        }
    }

    #pragma unroll
    for (int r = 0; r < 16; r++) {
        const int rowl = mi*32 + (r&3) + 8*(r>>2) + 4*lh;
        const int col  = n0 + ni*32 + l31;
        const float v  = acc[r] + bias[col];
        xg[(((size_t)d*64 + seq)*128 + sl0 + rowl)*1024 + col] = v;
    }
}

// ---------------------------------------------------------------------------
// Batch-split recurrent kernel (zero inter-block communication).
// 8 blocks = 2 dirs x 4 batch-groups of 16 sequences. 512 threads = 8 waves.
// Per step: gates(16 x 1024) = xg(precomputed) + h_prev(16x256) @ Whh^T via
// 512x mfma_16x16x32_bf16 per CU. Weight tiers per wave (8 ntiles of 16 cols):
//   j=0,1 (i-gate):  LDS-resident      (ntiles  0..15 block-wide, 128 KiB)
//   j=2,3 (f-gate):  VGPR-resident     (ntiles 16..31, 64 regs/wave)
//   j=4..7 (g,o):    streamed from L2  (ntiles 32..63, 256 KB/step, 2-deep dbuf)
// h double-buffered in LDS (1 barrier/step). c-state in regs, saved to ws at
// chunk boundaries (4 chunks x 128 steps per layer; xg slot = 67 MB fp32).
// ---------------------------------------------------------------------------
__global__ __launch_bounds__(512, 2)
void rec_kernel(const float* __restrict__ xg,
                const bf16* __restrict__ WpF, const bf16* __restrict__ WpB,
                bf16* __restrict__ hsout, float* __restrict__ cst, int chunk)
{
    extern __shared__ char smem[];
    bf16x8* Wlds = (bf16x8*)smem;              // 8192 frags = 128 KiB
    char* hb0 = smem + 131072;                 // 16 rows x 528 B (+16B pad: bank-safe)
    char* hb1 = hb0 + 8448;

    const int tid = threadIdx.x;
    const int w = tid >> 6, l = tid & 63;
    const int l15 = l & 15, lq = l >> 4;
    const int blk = blockIdx.x;
    const int d = blk >> 2, bg = blk & 3;
    const bf16x8* Wp = (const bf16x8*)(d ? WpB : WpF);

    // LDS-static weights: ntiles 0..15 (i-gate)
    for (int i = tid; i < 8192; i += 512) Wlds[i] = Wp[i];

    // VGPR-persistent weights: ntiles 16+w*2, 17+w*2 (f-gate)
    bf16x8 WR0[8], WR1[8];
    {
        const int b0 = (16 + w*2)*512 + l, b1 = b0 + 512;
        #pragma unroll
        for (int ks = 0; ks < 8; ks++) {
            WR0[ks] = Wp[b0 + ks*64];
            WR1[ks] = Wp[b1 + ks*64];
        }
    }

    // h buffer init
    if (chunk == 0) {
        uint4 z = make_uint4(0,0,0,0);
        for (int i = tid; i < 1056; i += 512) ((uint4*)hb0)[i] = z;
    } else {
        const int tprev = d ? (512 - chunk*128) : (chunk*128 - 1);
        const int seq = tid >> 5, col = (tid & 31)*8;
        uint4 v = *(const uint4*)(hsout
            + ((size_t)(bg*16+seq)*TSEQ + tprev)*512 + d*256 + col);
        *(uint4*)(hb0 + seq*528 + col*2) = v;
    }

    // c-state
    float cs[8];
    if (chunk == 0) {
        #pragma unroll
        for (int i = 0; i < 8; i++) cs[i] = 0.0f;
    } else {
        const float4 a = ((const float4*)cst)[(blk*512+tid)*2];
        const float4 b = ((const float4*)cst)[(blk*512+tid)*2+1];
        cs[0]=a.x; cs[1]=a.y; cs[2]=a.z; cs[3]=a.w;
        cs[4]=b.x; cs[5]=b.y; cs[6]=b.z; cs[7]=b.w;
    }

    // per-lane xg base: rows are seqs lq*4+r of this batch-group
    const float* xgl = xg + (size_t)(d*64 + bg*16 + lq*4) * 128 * 1024;

    // acc init = xg[sloc=0]
    floatx4 acc[8];
    #pragma unroll
    for (int j = 0; j < 8; j++) {
        const int nc = ((j>>1)*16 + w*2 + (j&1))*16 + l15;
        #pragma unroll
        for (int r = 0; r < 4; r++)
            acc[j][r] = __builtin_nontemporal_load(xgl + (size_t)r*131072 + nc);
    }

    // streamed ntile frag-index bases (frag idx = ntile*512 + ks*64 + l)
    const int sb0 = (32 + w*2)*512 + l;   // j=4 (g, u=0)
    const int sb1 = sb0 + 512;            // j=5 (g, u=1)
    const int sb2 = (48 + w*2)*512 + l;   // j=6 (o, u=0)
    const int sb3 = sb2 + 512;            // j=7 (o, u=1)
    bf16x8 SB0[8], SB1[8];
    #pragma unroll
    for (int ks = 0; ks < 8; ks++) SB0[ks] = Wp[sb0 + ks*64];
    #pragma unroll
    for (int ks = 0; ks < 8; ks++) SB1[ks] = Wp[sb1 + ks*64];

    __syncthreads();

    const int aoff = l15*528 + lq*16;          // A-frag: row=seq(l&15), k contiguous
    const int wl0 = (w*2)*512 + l, wl1 = wl0 + 512;

    for (int sl = 0; sl < 128; ++sl) {
        const int s = (chunk<<7) + sl;
        const int t = d ? (TSEQ-1 - s) : s;
        const char* hr = (sl & 1) ? hb1 : hb0;
        char* hw = (sl & 1) ? hb0 : hb1;

        bf16x8 A[8];
        #pragma unroll
        for (int ks = 0; ks < 8; ks++)
            A[ks] = *(const bf16x8*)(hr + aoff + ks*64);

        // i-gate from LDS
        #pragma unroll
        for (int ks = 0; ks < 8; ks++)
            acc[0] = __builtin_amdgcn_mfma_f32_16x16x32_bf16(A[ks], Wlds[wl0 + ks*64], acc[0], 0,0,0);
        #pragma unroll
        for (int ks = 0; ks < 8; ks++)
            acc[1] = __builtin_amdgcn_mfma_f32_16x16x32_bf16(A[ks], Wlds[wl1 + ks*64], acc[1], 0,0,0);
        // f-gate from persistent regs
        #pragma unroll
        for (int ks = 0; ks < 8; ks++)
            acc[2] = __builtin_amdgcn_mfma_f32_16x16x32_bf16(A[ks], WR0[ks], acc[2], 0,0,0);
        #pragma unroll
        for (int ks = 0; ks < 8; ks++)
            acc[3] = __builtin_amdgcn_mfma_f32_16x16x32_bf16(A[ks], WR1[ks], acc[3], 0,0,0);
        // g,o gates streamed (consume buffer, refill 2 tiles ahead)
        #pragma unroll
        for (int ks = 0; ks < 8; ks++)
            acc[4] = __builtin_amdgcn_mfma_f32_16x16x32_bf16(A[ks], SB0[ks], acc[4], 0,0,0);
        #pragma unroll
        for (int ks = 0; ks < 8; ks++) SB0[ks] = Wp[sb2 + ks*64];
        #pragma unroll
        for (int ks = 0; ks < 8; ks++)
            acc[5] = __builtin_amdgcn_mfma_f32_16x16x32_bf16(A[ks], SB1[ks], acc[5], 0,0,0);
        #pragma unroll
        for (int ks = 0; ks < 8; ks++) SB1[ks] = Wp[sb3 + ks*64];
        #pragma unroll
        for (int ks = 0; ks < 8; ks++)
            acc[6] = __builtin_amdgcn_mfma_f32_16x16x32_bf16(A[ks], SB0[ks], acc[6], 0,0,0);
        #pragma unroll
        for (int ks = 0; ks < 8; ks++) SB0[ks] = Wp[sb0 + ks*64];   // next step j=4
        #pragma unroll
        for (int ks = 0; ks < 8; ks++)
            acc[7] = __builtin_amdgcn_mfma_f32_16x16x32_bf16(A[ks], SB1[ks], acc[7], 0,0,0);
        #pragma unroll
        for (int ks = 0; ks < 8; ks++) SB1[ks] = Wp[sb1 + ks*64];   // next step j=5

        // gate math, fully in-register (C layout: seq=(l>>4)*4+r, col=nt*16+(l&15))
        float hvf[8];
        #pragma unroll
        for (int u = 0; u < 2; u++) {
            #pragma unroll
            for (int r = 0; r < 4; r++) {
                const float gi = acc[0+u][r], gf = acc[2+u][r];
                const float gg = acc[4+u][r], go = acc[6+u][r];
                const float cn = sigm(gf)*cs[u*4+r] + sigm(gi)*tanh_fast(gg);
                cs[u*4+r] = cn;
                hvf[u*4+r] = sigm(go)*tanh_fast(cn);
            }
        }

        // prefetch next step's xg into (now dead) acc regs — hides LLC latency
        if (sl < 127) {
            const float* xp = xgl + (size_t)(sl+1)*1024;
            #pragma unroll
            for (int j = 0; j < 8; j++) {
                const int nc = ((j>>1)*16 + w*2 + (j&1))*16 + l15;
                #pragma unroll
                for (int r = 0; r < 4; r++)
                    acc[j][r] = __builtin_nontemporal_load(xp + (size_t)r*131072 + nc);
            }
        }

        // h out: LDS (next step's A) + global hsout
        #pragma unroll
        for (int u = 0; u < 2; u++) {
            #pragma unroll
            for (int r = 0; r < 4; r++) {
                const bf16 hv = (bf16)hvf[u*4+r];
                const int seqr = lq*4 + r;
                const int col  = (w*2+u)*16 + l15;
                *(bf16*)(hw + seqr*528 + col*2) = hv;
                hsout[((size_t)(bg*16+seqr)*TSEQ + t)*512 + d*256 + col] = hv;
            }
        }
        __syncthreads();
    }

    const float4 sa = {cs[0],cs[1],cs[2],cs[3]};
    const float4 sb = {cs[4],cs[5],cs[6],cs[7]};
    ((float4*)cst)[(blk*512+tid)*2]   = sa;
    ((float4*)cst)[(blk*512+tid)*2+1] = sb;
}

// ---------------------------------------------------------------------------
// Shared 64x64 bf16 GEMM main loop (attention chain) — unchanged.
// ---------------------------------------------------------------------------
__device__ __forceinline__ floatx16 gemm_loop(const bf16* __restrict__ A0,
                                              const bf16* __restrict__ Bt0,
                                              int lda, int ldb, int K, int brows,
                                              char* smem)
{
    const int tid = threadIdx.x;
    const int wave = tid >> 6, lane = tid & 63;
    const int mi = wave & 1, ni = wave >> 1;
    const int l31 = lane & 31, lh = lane >> 5;
    char* At = smem;
    char* Bt = smem + 64*144;
    floatx16 acc;
    #pragma unroll
    for (int r = 0; r < 16; r++) acc[r] = 0.0f;

    for (int kc = 0; kc < K; kc += 64) {
        __syncthreads();
        for (int c = tid; c < 1024; c += 256) {
            int which = c >> 9;
            int idx = c & 511;
            int row = idx >> 3, kch = idx & 7;
            uint4 v;
            if (which == 0) {
                v = *(const uint4*)(A0 + (size_t)row*lda + kc + kch*8);
                *(uint4*)(At + row*144 + kch*16) = v;
            } else {
                if (row < brows) v = *(const uint4*)(Bt0 + (size_t)row*ldb + kc + kch*8);
                else             v = make_uint4(0,0,0,0);
                *(uint4*)(Bt + row*144 + kch*16) = v;
            }
        }
        __syncthreads();
        #pragma unroll
        for (int ks = 0; ks < 4; ks++) {
            bf16x8 a = *(const bf16x8*)(At + (mi*32 + l31)*144 + ks*32 + lh*16);
            bf16x8 b = *(const bf16x8*)(Bt + (ni*32 + l31)*144 + ks*32 + lh*16);
            acc = __builtin_amdgcn_mfma_f32_32x32x16_bf16(a, b, acc, 0, 0, 0);
        }
    }
    return acc;
}

__global__ __launch_bounds__(256, 2)
void sgemm_scores(const bf16* __restrict__ hs1, float* __restrict__ S)
{
    __shared__ char smem[64*144*2];
    int n = blockIdx.z, tm = blockIdx.x, tn = blockIdx.y;
    const bf16* base = hs1 + (size_t)n*512*512;
    floatx16 acc = gemm_loop(base + (size_t)tm*64*512, base + (size_t)tn*64*512,
                             512, 512, 512, 64, smem);
    int wave = threadIdx.x >> 6, lane = threadIdx.x & 63;
    int mi = wave & 1, ni = wave >> 1;
    #pragma unroll
    for (int r = 0; r < 16; r++) {
        int row = tm*64 + mi*32 + (r&3) + 8*(r>>2) + 4*(lane>>5);
        int col = tn*64 + ni*32 + (lane&31);
        S[(size_t)n*512*512 + (size_t)row*512 + col] = acc[r];
    }
}

__global__ __launch_bounds__(256, 4)
void softmax_rows(const float* __restrict__ S, bf16* __restrict__ P)
{
    int row = blockIdx.x*4 + (threadIdx.x >> 6);
    int lane = threadIdx.x & 63;
    const float* src = S + (size_t)row*512 + lane*8;
    float4 a = *(const float4*)(src);
    float4 b = *(const float4*)(src + 4);
    float v[8] = {a.x,a.y,a.z,a.w,b.x,b.y,b.z,b.w};
    float m = v[0];
    #pragma unroll
    for (int j = 1; j < 8; j++) m = fmaxf(m, v[j]);
    #pragma unroll
    for (int off = 32; off > 0; off >>= 1) m = fmaxf(m, __shfl_xor(m, off));
    float s = 0.0f;
    #pragma unroll
    for (int j = 0; j < 8; j++) { v[j] = __expf(v[j]-m); s += v[j]; }
    #pragma unroll
    for (int off = 32; off > 0; off >>= 1) s += __shfl_xor(s, off);
    float inv = 1.0f/s;
    union { uint4 u; bf16 h[8]; } pk;
    #pragma unroll
    for (int j = 0; j < 8; j++) pk.h[j] = (bf16)(v[j]*inv);
    *(uint4*)(P + (size_t)row*512 + lane*8) = pk.u;
}

__global__ __launch_bounds__(256, 2)
void transpose_nt(const bf16* __restrict__ hs1, bf16* __restrict__ hs1T)
{
    __shared__ bf16 tile[64][72];
    int n = blockIdx.z, tX = blockIdx.x, fX = blockIdx.y;
    const bf16* src = hs1 + (size_t)n*512*512;
    for (int c = threadIdx.x; c < 512; c += 256) {
        int row = c >> 3, kch = c & 7;
        *(uint4*)(&tile[row][kch*8]) =
            *(const uint4*)(src + (size_t)(tX*64+row)*512 + fX*64 + kch*8);
    }
    __syncthreads();
    bf16* dst = hs1T + (size_t)n*512*512;
    for (int c = threadIdx.x; c < 512; c += 256) {
        int frow = c >> 3, tch = c & 7;
        bf16 tmp[8];
        #pragma unroll
        for (int j = 0; j < 8; j++) tmp[j] = tile[tch*8+j][frow];
        *(uint4*)(dst + (size_t)(fX*64+frow)*512 + tX*64 + tch*8) = *(uint4*)tmp;
    }
}

__global__ __launch_bounds__(256, 2)
void ctx_gemm(const bf16* __restrict__ P, const bf16* __restrict__ hs1T,
              bf16* __restrict__ ctx)
{
    __shared__ char smem[64*144*2];
    int n = blockIdx.z, tm = blockIdx.x, tn = blockIdx.y;
    const bf16* A0 = P    + (size_t)n*512*512 + (size_t)tm*64*512;
    const bf16* B0 = hs1T + (size_t)n*512*512 + (size_t)tn*64*512;
    floatx16 acc = gemm_loop(A0, B0, 512, 512, 512, 64, smem);
    int wave = threadIdx.x >> 6, lane = threadIdx.x & 63;
    int mi = wave & 1, ni = wave >> 1;
    #pragma unroll
    for (int r = 0; r < 16; r++) {
        int row = tm*64 + mi*32 + (r&3) + 8*(r>>2) + 4*(lane>>5);
        int col = tn*64 + ni*32 + (lane&31);
        ctx[((size_t)n*512 + row)*512 + col] = (bf16)acc[r];
    }
}

__global__ __launch_bounds__(256, 2)
void fc1_gemm(const bf16* __restrict__ ctx, const bf16* __restrict__ hs1,
              const bf16* __restrict__ wb, const float* __restrict__ b,
              float* __restrict__ outp)
{
    __shared__ char smem[64*144*2];
    const int tid = threadIdx.x;
    const int wave = tid >> 6, lane = tid & 63;
    const int mi = wave & 1, ni = wave >> 1;
    const int l31 = lane & 31, lh = lane >> 5;
    char* At = smem;
    char* Bt = smem + 64*144;
    const int m0 = blockIdx.x*64;
    floatx16 acc;
    #pragma unroll
    for (int r = 0; r < 16; r++) acc[r] = 0.0f;

    for (int kc = 0; kc < 1024; kc += 64) {
        const bf16* Asrc = (kc < 512) ? ctx : hs1;
        const int koff = kc & 511;
        __syncthreads();
        for (int c = tid; c < 1024; c += 256) {
            int which = c >> 9, idx = c & 511;
            int row = idx >> 3, kch = idx & 7;
            uint4 v;
            if (which == 0) {
                v = *(const uint4*)(Asrc + (size_t)(m0+row)*512 + koff + kch*8);
                *(uint4*)(At + row*144 + kch*16) = v;
            } else {
                if (row < 50) v = *(const uint4*)(wb + (size_t)row*1024 + kc + kch*8);
                else          v = make_uint4(0,0,0,0);
                *(uint4*)(Bt + row*144 + kch*16) = v;
            }
        }
        __syncthreads();
        #pragma unroll
        for (int ks = 0; ks < 4; ks++) {
            bf16x8 a = *(const bf16x8*)(At + (mi*32 + l31)*144 + ks*32 + lh*16);
            bf16x8 bb = *(const bf16x8*)(Bt + (ni*32 + l31)*144 + ks*32 + lh*16);
            acc = __builtin_amdgcn_mfma_f32_32x32x16_bf16(a, bb, acc, 0, 0, 0);
        }
    }
    #pragma unroll
    for (int r = 0; r < 16; r++) {
        int row = m0 + mi*32 + (r&3) + 8*(r>>2) + 4*lh;
        int col = ni*32 + l31;
        if (col < 50) {
            float v = acc[r] + b[col];
            outp[(size_t)row*50 + col] = fmaxf(v, 0.0f);
        }
    }
}

__global__ __launch_bounds__(256, 4)
void bn_stats(const float* __restrict__ fc1out, float* __restrict__ stats)
{
    __shared__ float sh[512];
    int c = blockIdx.x;
    float s = 0.0f, ss = 0.0f;
    for (int i = threadIdx.x; i < 32768; i += 256) {
        int n = i >> 9, q = i & 511;
        float x = fc1out[(size_t)n*25600 + c*512 + q];
        s += x; ss += x*x;
    }
    sh[threadIdx.x] = s; sh[256 + threadIdx.x] = ss;
    __syncthreads();
    for (int o = 128; o > 0; o >>= 1) {
        if (threadIdx.x < o) {
            sh[threadIdx.x] += sh[threadIdx.x + o];
            sh[256+threadIdx.x] += sh[256+threadIdx.x + o];
        }
        __syncthreads();
    }
    if (threadIdx.x == 0) {
        float mean = sh[0] / 32768.0f;
        float var  = sh[256] / 32768.0f - mean*mean;
        stats[c]      = mean;
        stats[64 + c] = rsqrtf(var + 1e-5f);
    }
}

__global__ __launch_bounds__(256, 4)
void tail_kernel(const float* __restrict__ fc1out, const float* __restrict__ stats,
                 const float* __restrict__ bng, const float* __restrict__ bnb,
                 const float* __restrict__ fc2w, const float* __restrict__ fc2b,
                 const float* __restrict__ fc3w, const float* __restrict__ fc3b,
                 const float* __restrict__ fc4w, const float* __restrict__ fc4b,
                 float* __restrict__ outp)
{
    __shared__ float W2[1250], W3[250], B2[25], B3[10], W4[20], B4[2];
    __shared__ float G[50], Bb[50], MU[50], IS[50];
    for (int i = threadIdx.x; i < 1250; i += 256) W2[i] = fc2w[i];
    for (int i = threadIdx.x; i < 250;  i += 256) W3[i] = fc3w[i];
    if (threadIdx.x < 25) B2[threadIdx.x] = fc2b[threadIdx.x];
    if (threadIdx.x < 20) W4[threadIdx.x] = fc4w[threadIdx.x];
    if (threadIdx.x < 10) B3[threadIdx.x] = fc3b[threadIdx.x];
    if (threadIdx.x < 2)  B4[threadIdx.x] = fc4b[threadIdx.x];
    if (threadIdx.x < 50) {
        G[threadIdx.x]  = bng[threadIdx.x];
        Bb[threadIdx.x] = bnb[threadIdx.x];
        MU[threadIdx.x] = stats[threadIdx.x];
        IS[threadIdx.x] = stats[64 + threadIdx.x];
    }
    __syncthreads();
    int m = blockIdx.x*256 + threadIdx.x;
    int t = m & 511;
    const float* src = fc1out + (size_t)m*50;
    float x[50];
    #pragma unroll
    for (int c = 0; c < 50; c++) {
        int j = (t*50 + c) >> 9;
        x[c] = (src[c] - MU[j])*IS[j]*G[j] + Bb[j];
    }
    float y2[25];
    #pragma unroll
    for (int o = 0; o < 25; o++) {
        float a = B2[o];
        for (int c = 0; c < 50; c++) a += x[c]*W2[o*50+c];
        y2[o] = fmaxf(a, 0.0f);
    }
    float y3[10];
    #pragma unroll
    for (int o = 0; o < 10; o++) {
        float a = B3[o];
        for (int c = 0; c < 25; c++) a += y2[c]*W3[o*25+c];
        y3[o] = fmaxf(a, 0.0f);
    }
    #pragma unroll
    for (int o = 0; o < 2; o++) {
        float a = B4[o];
        for (int c = 0; c < 10; c++) a += y3[c]*W4[o*10+c];
        outp[(size_t)m*2 + o] = a;
    }
}

extern "C" void kernel_launch(void* const* d_in, const int* in_sizes, int n_in,
                              void* d_out, int out_size, void* d_ws, size_t ws_size,
                              hipStream_t stream)
{
    const float* x       = (const float*)d_in[0];
    const float* wih_l0f = (const float*)d_in[1];
    const float* whh_l0f = (const float*)d_in[2];
    const float* b_l0f   = (const float*)d_in[3];
    const float* wih_l0b = (const float*)d_in[4];
    const float* whh_l0b = (const float*)d_in[5];
    const float* b_l0b   = (const float*)d_in[6];
    const float* wih_l1f = (const float*)d_in[7];
    const float* whh_l1f = (const float*)d_in[8];
    const float* b_l1f   = (const float*)d_in[9];
    const float* wih_l1b = (const float*)d_in[10];
    const float* whh_l1b = (const float*)d_in[11];
    const float* b_l1b   = (const float*)d_in[12];
    const float* fc1w    = (const float*)d_in[13];
    const float* fc1b    = (const float*)d_in[14];
    const float* bng     = (const float*)d_in[15];
    const float* bnb     = (const float*)d_in[16];
    const float* fc2w    = (const float*)d_in[17];
    const float* fc2b    = (const float*)d_in[18];
    const float* fc3w    = (const float*)d_in[19];
    const float* fc3b    = (const float*)d_in[20];
    const float* fc4w    = (const float*)d_in[21];
    const float* fc4b    = (const float*)d_in[22];

    // ---- workspace layout (total 208,011,264 B <= previous 208,015,360) ----
    char* ws = (char*)d_ws;
    float* stats  = (float*)ws;                        // 512 B
    bf16*  fc1wb  = (bf16*)(ws + 4096);                // 102400 B
    bf16*  hs0    = (bf16*)(ws + 131072);              // 32 MiB
    bf16*  hs1    = (bf16*)(ws + 33685504);            // 32 MiB
    // rec-phase region (reused by attention buffers afterwards):
    float* xgA    = (float*)(ws + 67239936);           // 64 MiB
    float* xgB    = (float*)(ws + 134348800);          // 64 MiB
    bf16*  wb0f   = (bf16*)(ws + 201457664);           // 256 KiB
    bf16*  wb0b   = (bf16*)(ws + 201719808);           // 256 KiB
    bf16*  wb1f   = (bf16*)(ws + 201981952);           // 1 MiB
    bf16*  wb1b   = (bf16*)(ws + 203030528);           // 1 MiB
    bf16*  Wp0f   = (bf16*)(ws + 204079104);           // 512 KiB
    bf16*  Wp0b   = (bf16*)(ws + 204603392);           // 512 KiB
    bf16*  Wp1f   = (bf16*)(ws + 205127680);           // 512 KiB
    bf16*  Wp1b   = (bf16*)(ws + 205651968);           // 512 KiB
    float* cst    = (float*)(ws + 206176256);          // 128 KiB
    // post-rec overlays (xg/packs dead by then):
    bf16*  ctx    = (bf16*)(ws + 67239936);            // 32 MiB
    float* S      = (float*)(ws + 100794368);          // 64 MiB
    bf16*  P      = (bf16*)(ws + 167903232);           // 32 MiB
    float* fc1out = (float*)(ws + 201457664);          // 6.25 MiB
    bf16*  hs1T   = (bf16*)S;                          // overlays S (dead after softmax)

    // ---- weight prep ----
    f2b_kernel<<<200, 256, 0, stream>>>(fc1w, fc1wb, 51200);
    f2b_kernel<<<512, 256, 0, stream>>>(wih_l0f, wb0f, 131072);
    f2b_kernel<<<512, 256, 0, stream>>>(wih_l0b, wb0b, 131072);
    f2b_kernel<<<2048, 256, 0, stream>>>(wih_l1f, wb1f, 524288);
    f2b_kernel<<<2048, 256, 0, stream>>>(wih_l1b, wb1b, 524288);
    pack_whh<<<128, 256, 0, stream>>>(whh_l0f, Wp0f);
    pack_whh<<<128, 256, 0, stream>>>(whh_l0b, Wp0b);
    pack_whh<<<128, 256, 0, stream>>>(whh_l1f, Wp1f);
    pack_whh<<<128, 256, 0, stream>>>(whh_l1b, Wp1b);

    constexpr int REC_LDS = 131072 + 2*8448;   // 147968 B
    hipFuncSetAttribute(reinterpret_cast<const void*>(&rec_kernel),
                        hipFuncAttributeMaxDynamicSharedMemorySize, REC_LDS);

    dim3 gx(128, 16, 2);
    // layer 0
    for (int c = 0; c < 4; c++) {
        float* xgc = (c & 1) ? xgB : xgA;
        xg_gemm<128, true><<<gx, 256, 0, stream>>>(x, wb0f, wb0b, b_l0f, b_l0b, xgc, c);
        rec_kernel<<<8, 512, REC_LDS, stream>>>(xgc, Wp0f, Wp0b, hs0, cst, c);
    }
    // layer 1
    for (int c = 0; c < 4; c++) {
        float* xgc = (c & 1) ? xgB : xgA;
        xg_gemm<512, false><<<gx, 256, 0, stream>>>(hs0, wb1f, wb1b, b_l1f, b_l1b, xgc, c);
        rec_kernel<<<8, 512, REC_LDS, stream>>>(xgc, Wp1f, Wp1b, hs1, cst, c);
    }

    // ---- attention + head (unchanged) ----
    dim3 g88(8, 8, 64);
    sgemm_scores<<<g88, 256, 0, stream>>>(hs1, S);
    softmax_rows<<<8192, 256, 0, stream>>>(S, P);
    transpose_nt<<<g88, 256, 0, stream>>>(hs1, hs1T);
    ctx_gemm<<<g88, 256, 0, stream>>>(P, hs1T, ctx);
    fc1_gemm<<<512, 256, 0, stream>>>(ctx, hs1, fc1wb, fc1b, fc1out);
    bn_stats<<<50, 256, 0, stream>>>(fc1out, stats);
    tail_kernel<<<128, 256, 0, stream>>>(fc1out, stats, bng, bnb, fc2w, fc2b,
                                         fc3w, fc3b, fc4w, fc4b, (float*)d_out);
    (void)in_sizes; (void)n_in; (void)out_size; (void)ws_size;
}

// Round 2
// 5661.556 us; speedup vs baseline: 2.0118x; 2.0118x over previous
//
#include <hip/hip_runtime.h>
#include <hip/hip_bf16.h>

typedef __bf16 bf16;
typedef __bf16 bf16x8 __attribute__((ext_vector_type(8)));
typedef float floatx4 __attribute__((ext_vector_type(4)));
typedef float floatx16 __attribute__((ext_vector_type(16)));

#define TSEQ 512
#define MFMA16 __builtin_amdgcn_mfma_f32_16x16x32_bf16

__device__ __forceinline__ float sigm(float x){ return 1.0f/(1.0f + __expf(-x)); }
__device__ __forceinline__ float tanh_fast(float x){
    float e = __expf(2.0f*x);
    return 1.0f - 2.0f/(e + 1.0f);   // correct limits at +-inf
}

// fp32 -> bf16 converter
__global__ __launch_bounds__(256, 4)
void f2b_kernel(const float* __restrict__ in, bf16* __restrict__ out, int n)
{
    int i = blockIdx.x*256 + threadIdx.x;
    if (i < n) out[i] = (bf16)in[i];
}

// ---------------------------------------------------------------------------
// Pack Whh (1024 x 256 fp32) into MFMA-16x16x32 B-frag-major bf16 layout:
// Wp[ntile 0..63][kstep 0..7][lane 0..63][e 0..7], value =
//   Whh[gatecol = ntile*16 + (lane&15)][k = kstep*32 + (lane>>4)*8 + e]
// ---------------------------------------------------------------------------
__global__ __launch_bounds__(256, 4)
void pack_whh(const float* __restrict__ whh, bf16* __restrict__ wp)
{
    int idx = blockIdx.x*256 + threadIdx.x;
    if (idx >= 32768) return;
    int lane = idx & 63, ks = (idx >> 6) & 7, nt = idx >> 9;
    int row = nt*16 + (lane & 15);
    int k0  = ks*32 + (lane >> 4)*8;
    const float* src = whh + (size_t)row*256 + k0;
    bf16x8 v;
    #pragma unroll
    for (int e = 0; e < 8; e++) v[e] = (bf16)src[e];
    ((bf16x8*)wp)[idx] = v;
}

// ---------------------------------------------------------------------------
// Fused recurrent + next-chunk xg kernel.
// Blocks [0, nrec): batch-split BiLSTM recurrence, chunk cr (128 steps).
//   8 blocks = 2 dirs x 4 batch-groups of 16 seqs, 512 thr = 8 waves.
//   Per step, gates(16x1024) = xg + h_prev(16x256) @ Whh^T:
//     j=0,1 (i-gate): LDS-resident weights (16 ntiles, 128 KiB)
//     j=2..5 (f,g):   VGPR-resident WV[4][8] (128 regs)
//     j=6,7 (o):      streamed from L2 through SB[8] (2 refills/step)
//   xg prefetched into acc (acc = MFMA C-in) with coalesced [r][j][tid] layout.
// Blocks [nrec, ...): xg GEMM for chunk cx (two 64x64 tiles per block,
//   half-block each), writing xg_w in the rec-thread-matched layout.
// xg slab layout (per chunk): [(d*4+bg)*128 + sloc][re 0..3][je 0..7][tid 0..511]
// ---------------------------------------------------------------------------
template<int DIN, bool XF32>
__global__ __launch_bounds__(512, 1)
void fused_kernel(int nrec,
                  const float* __restrict__ xg_r,
                  const bf16* __restrict__ WpF, const bf16* __restrict__ WpB,
                  bf16* __restrict__ hsout, float* __restrict__ cst, int cr,
                  const void* __restrict__ xin,
                  const bf16* __restrict__ wbf, const bf16* __restrict__ wbb,
                  const float* __restrict__ bf_, const float* __restrict__ bb_,
                  float* __restrict__ xg_w, int cx, int nxg)
{
    extern __shared__ char smem[];
    if ((int)blockIdx.x < nrec) {
        // ================= REC branch =================
        bf16x8* Wlds = (bf16x8*)smem;          // 8192 frags = 128 KiB
        char* hb0 = smem + 131072;             // 16 rows x 528 B
        char* hb1 = hb0 + 8448;

        const int tid = threadIdx.x;
        const int w = tid >> 6, l = tid & 63;
        const int l15 = l & 15, lq = l >> 4;
        const int blk = blockIdx.x;
        const int d = blk >> 2, bg = blk & 3;
        const bf16x8* Wp = (const bf16x8*)(d ? WpB : WpF);

        // LDS tier: ntiles 0..15 (i-gate)
        for (int i = tid; i < 8192; i += 512) Wlds[i] = Wp[i];

        // VGPR tier: j=2..5 (f,g gates)
        bf16x8 WV[4][8];
        {
            const int nta0 = 16 + 2*w, nta1 = 17 + 2*w;
            const int nta2 = 32 + 2*w, nta3 = 33 + 2*w;
            #pragma unroll
            for (int ks = 0; ks < 8; ks++) {
                WV[0][ks] = Wp[nta0*512 + ks*64 + l];
                WV[1][ks] = Wp[nta1*512 + ks*64 + l];
                WV[2][ks] = Wp[nta2*512 + ks*64 + l];
                WV[3][ks] = Wp[nta3*512 + ks*64 + l];
            }
        }
        // streamed tier bases: j=6 -> nt6, j=7 -> nt7 (o-gate)
        const int nt6 = 48 + 2*w, nt7 = 49 + 2*w;
        bf16x8 SB[8];
        #pragma unroll
        for (int ks = 0; ks < 8; ks++) SB[ks] = Wp[nt6*512 + ks*64 + l];

        // h buffer init
        if (cr == 0) {
            uint4 z = make_uint4(0,0,0,0);
            for (int i = tid; i < 1056; i += 512) ((uint4*)hb0)[i] = z;
        } else {
            const int tprev = d ? (512 - cr*128) : (cr*128 - 1);
            const int sq = tid >> 5, col = (tid & 31) * 8;
            uint4 v = *(const uint4*)(hsout
                + ((size_t)(bg*16+sq)*TSEQ + tprev)*512 + d*256 + col);
            *(uint4*)(hb0 + sq*528 + col*2) = v;
        }

        // c-state
        float cs[8];
        if (cr == 0) {
            #pragma unroll
            for (int i = 0; i < 8; i++) cs[i] = 0.0f;
        } else {
            const float4 a = ((const float4*)cst)[(blk*512+tid)*2];
            const float4 b = ((const float4*)cst)[(blk*512+tid)*2+1];
            cs[0]=a.x; cs[1]=a.y; cs[2]=a.z; cs[3]=a.w;
            cs[4]=b.x; cs[5]=b.y; cs[6]=b.z; cs[7]=b.w;
        }

        // acc init = xg(sl=0); acc doubles as xg prefetch buffer
        const float* slab = xg_r + (size_t)(d*4 + bg) * 128 * 16384;
        floatx4 acc[8];
        #pragma unroll
        for (int j = 0; j < 8; j++)
            #pragma unroll
            for (int r = 0; r < 4; r++)
                acc[j][r] = slab[r*4096 + j*512 + tid];

        __syncthreads();

        const int aoff0 = l15*528 + lq*16;
        const int wb0i = (2*w)*512 + l, wb1i = (2*w+1)*512 + l;

        for (int sl = 0; sl < 128; ++sl) {
            const int t = d ? (511 - (cr*128 + sl)) : (cr*128 + sl);
            const char* hr = (sl & 1) ? hb1 : hb0;
            char* hw = (sl & 1) ? hb0 : hb1;
            const float* slabN = slab + 16384;

            // opaque zero: defeats LICM hoisting of the SB refills
            int zx;
            asm volatile("s_mov_b32 %0, 0" : "=s"(zx));

            // ---- P1: j=0..5 (LDS + WV), rolling A ----
            bf16x8 Ac = *(const bf16x8*)(hr + aoff0);
            #pragma unroll
            for (int ks = 0; ks < 8; ks++) {
                bf16x8 An = Ac;
                if (ks < 7) An = *(const bf16x8*)(hr + aoff0 + (ks+1)*64);
                acc[0] = MFMA16(Ac, Wlds[wb0i + ks*64], acc[0], 0,0,0);
                acc[1] = MFMA16(Ac, Wlds[wb1i + ks*64], acc[1], 0,0,0);
                acc[2] = MFMA16(Ac, WV[0][ks], acc[2], 0,0,0);
                acc[3] = MFMA16(Ac, WV[1][ks], acc[3], 0,0,0);
                acc[4] = MFMA16(Ac, WV[2][ks], acc[4], 0,0,0);
                acc[5] = MFMA16(Ac, WV[3][ks], acc[5], 0,0,0);
                Ac = An;
            }
            // ---- P2: j=6 from SB ----
            Ac = *(const bf16x8*)(hr + aoff0);
            #pragma unroll
            for (int ks = 0; ks < 8; ks++) {
                bf16x8 An = Ac;
                if (ks < 7) An = *(const bf16x8*)(hr + aoff0 + (ks+1)*64);
                acc[6] = MFMA16(Ac, SB[ks], acc[6], 0,0,0);
                Ac = An;
            }
            // refill SB with j=7 (consumed after ph1 -> latency covered)
            #pragma unroll
            for (int ks = 0; ks < 8; ks++) SB[ks] = Wp[nt7*512 + ks*64 + l + zx];

            // ---- ph1: cn = sigm(f)*c + sigm(i)*tanh(g) ----
            #pragma unroll
            for (int u = 0; u < 2; u++)
                #pragma unroll
                for (int r = 0; r < 4; r++) {
                    const float gi = acc[0+u][r], gf = acc[2+u][r], gg = acc[4+u][r];
                    cs[u*4+r] = sigm(gf)*cs[u*4+r] + sigm(gi)*tanh_fast(gg);
                }
            // prefetch xg(s+1) into freed acc[0..5]
            if (sl < 127) {
                #pragma unroll
                for (int j = 0; j < 6; j++)
                    #pragma unroll
                    for (int r = 0; r < 4; r++)
                        acc[j][r] = slabN[r*4096 + j*512 + tid];
            }
            // ---- P3: j=7 from SB ----
            Ac = *(const bf16x8*)(hr + aoff0);
            #pragma unroll
            for (int ks = 0; ks < 8; ks++) {
                bf16x8 An = Ac;
                if (ks < 7) An = *(const bf16x8*)(hr + aoff0 + (ks+1)*64);
                acc[7] = MFMA16(Ac, SB[ks], acc[7], 0,0,0);
                Ac = An;
            }
            // refill SB with j=6 for next step (max latency cover)
            #pragma unroll
            for (int ks = 0; ks < 8; ks++) SB[ks] = Wp[nt6*512 + ks*64 + l + zx];

            // ---- ph2: h = sigm(o)*tanh(cn); stores ----
            #pragma unroll
            for (int u = 0; u < 2; u++)
                #pragma unroll
                for (int r = 0; r < 4; r++) {
                    const float go = acc[6+u][r];
                    const float hv = sigm(go)*tanh_fast(cs[u*4+r]);
                    const bf16 hb = (bf16)hv;
                    const int seqr = lq*4 + r;
                    const int col  = (w*2+u)*16 + l15;
                    *(bf16*)(hw + seqr*528 + col*2) = hb;
                    hsout[((size_t)(bg*16+seqr)*TSEQ + t)*512 + d*256 + col] = hb;
                }
            if (sl < 127) {
                #pragma unroll
                for (int j = 6; j < 8; j++)
                    #pragma unroll
                    for (int r = 0; r < 4; r++)
                        acc[j][r] = slabN[r*4096 + j*512 + tid];
            }
            slab = slabN;
            __syncthreads();
        }

        const float4 sa = {cs[0],cs[1],cs[2],cs[3]};
        const float4 sb = {cs[4],cs[5],cs[6],cs[7]};
        ((float4*)cst)[(blk*512+tid)*2]   = sa;
        ((float4*)cst)[(blk*512+tid)*2+1] = sb;
    } else {
        // ================= XG branch =================
        const int xb = (int)blockIdx.x - nrec;
        if (xb < 0 || xb*2 >= nxg) return;
        const int half = threadIdx.x >> 8, lt = threadIdx.x & 255;
        char* At = smem + half*18432;
        char* Bt = At + 9216;
        const int t4 = xb*2 + half;
        const int dd = t4 >> 11;
        const int rem = t4 & 2047;
        const int seq = rem >> 5;
        const int rem2 = rem & 31;
        const int colt = rem2 >> 1, slh = rem2 & 1;
        const int wv = lt >> 6, ln = lt & 63;
        const int mi = wv & 1, ni = wv >> 1;
        const int l31 = ln & 31, lh = ln >> 5;
        const bf16*  wb   = dd ? wbb : wbf;
        const float* bias = dd ? bb_ : bf_;
        const int sl0 = slh*64, n0 = colt*64;
        const int t0  = dd ? (511 - (cx*128 + sl0)) : (cx*128 + sl0);
        const int stp = dd ? -1 : 1;

        floatx16 acc;
        #pragma unroll
        for (int r = 0; r < 16; r++) acc[r] = 0.0f;

        for (int kc = 0; kc < DIN; kc += 64) {
            __syncthreads();
            for (int c = lt; c < 1024; c += 256) {
                const int which = c >> 9, idx = c & 511;
                const int row = idx >> 3, k8 = idx & 7;
                if (which == 0) {
                    const int trow = t0 + row*stp;
                    if constexpr (XF32) {
                        const float* src = (const float*)xin
                            + ((size_t)seq*TSEQ + trow)*DIN + kc + k8*8;
                        const float4 lo = *(const float4*)src;
                        const float4 hi = *(const float4*)(src+4);
                        bf16 tmp[8] = {(bf16)lo.x,(bf16)lo.y,(bf16)lo.z,(bf16)lo.w,
                                       (bf16)hi.x,(bf16)hi.y,(bf16)hi.z,(bf16)hi.w};
                        *(uint4*)(At + row*144 + k8*16) = *(uint4*)tmp;
                    } else {
                        const bf16* src = (const bf16*)xin
                            + ((size_t)seq*TSEQ + trow)*DIN + kc + k8*8;
                        *(uint4*)(At + row*144 + k8*16) = *(const uint4*)src;
                    }
                } else {
                    *(uint4*)(Bt + row*144 + k8*16) =
                        *(const uint4*)(wb + (size_t)(n0+row)*DIN + kc + k8*8);
                }
            }
            __syncthreads();
            #pragma unroll
            for (int ks = 0; ks < 4; ks++) {
                bf16x8 a = *(const bf16x8*)(At + (mi*32 + l31)*144 + ks*32 + lh*16);
                bf16x8 b = *(const bf16x8*)(Bt + (ni*32 + l31)*144 + ks*32 + lh*16);
                acc = __builtin_amdgcn_mfma_f32_32x32x16_bf16(a, b, acc, 0, 0, 0);
            }
        }
        // epilogue: scatter into rec-matched layout [slab][re][je][tid]
        const int s16 = seq & 15, lqe = s16 >> 2, re = s16 & 3, bge = seq >> 4;
        const int col = n0 + ni*32 + l31;
        const int nt = col >> 4, l15e = col & 15;
        const int we = (nt >> 1) & 7, je = ((nt >> 4) << 1) | (nt & 1);
        const int tide = we*64 + lqe*16 + l15e;
        float* dst = xg_w + (size_t)(dd*4 + bge) * 128 * 16384
                     + re*4096 + je*512 + tide;
        const float bv = bias[col];
        #pragma unroll
        for (int r = 0; r < 16; r++) {
            const int rowl = mi*32 + (r&3) + 8*(r>>2) + 4*lh;
            dst[(size_t)(sl0 + rowl) * 16384] = acc[r] + bv;
        }
    }
}

// ---------------------------------------------------------------------------
// Shared 64x64 bf16 GEMM main loop (attention chain) — unchanged.
// ---------------------------------------------------------------------------
__device__ __forceinline__ floatx16 gemm_loop(const bf16* __restrict__ A0,
                                              const bf16* __restrict__ Bt0,
                                              int lda, int ldb, int K, int brows,
                                              char* smem)
{
    const int tid = threadIdx.x;
    const int wave = tid >> 6, lane = tid & 63;
    const int mi = wave & 1, ni = wave >> 1;
    const int l31 = lane & 31, lh = lane >> 5;
    char* At = smem;
    char* Bt = smem + 64*144;
    floatx16 acc;
    #pragma unroll
    for (int r = 0; r < 16; r++) acc[r] = 0.0f;

    for (int kc = 0; kc < K; kc += 64) {
        __syncthreads();
        for (int c = tid; c < 1024; c += 256) {
            int which = c >> 9;
            int idx = c & 511;
            int row = idx >> 3, kch = idx & 7;
            uint4 v;
            if (which == 0) {
                v = *(const uint4*)(A0 + (size_t)row*lda + kc + kch*8);
                *(uint4*)(At + row*144 + kch*16) = v;
            } else {
                if (row < brows) v = *(const uint4*)(Bt0 + (size_t)row*ldb + kc + kch*8);
                else             v = make_uint4(0,0,0,0);
                *(uint4*)(Bt + row*144 + kch*16) = v;
            }
        }
        __syncthreads();
        #pragma unroll
        for (int ks = 0; ks < 4; ks++) {
            bf16x8 a = *(const bf16x8*)(At + (mi*32 + l31)*144 + ks*32 + lh*16);
            bf16x8 b = *(const bf16x8*)(Bt + (ni*32 + l31)*144 + ks*32 + lh*16);
            acc = __builtin_amdgcn_mfma_f32_32x32x16_bf16(a, b, acc, 0, 0, 0);
        }
    }
    return acc;
}

__global__ __launch_bounds__(256, 2)
void sgemm_scores(const bf16* __restrict__ hs1, float* __restrict__ S)
{
    __shared__ char smem[64*144*2];
    int n = blockIdx.z, tm = blockIdx.x, tn = blockIdx.y;
    const bf16* base = hs1 + (size_t)n*512*512;
    floatx16 acc = gemm_loop(base + (size_t)tm*64*512, base + (size_t)tn*64*512,
                             512, 512, 512, 64, smem);
    int wave = threadIdx.x >> 6, lane = threadIdx.x & 63;
    int mi = wave & 1, ni = wave >> 1;
    #pragma unroll
    for (int r = 0; r < 16; r++) {
        int row = tm*64 + mi*32 + (r&3) + 8*(r>>2) + 4*(lane>>5);
        int col = tn*64 + ni*32 + (lane&31);
        S[(size_t)n*512*512 + (size_t)row*512 + col] = acc[r];
    }
}

__global__ __launch_bounds__(256, 4)
void softmax_rows(const float* __restrict__ S, bf16* __restrict__ P)
{
    int row = blockIdx.x*4 + (threadIdx.x >> 6);
    int lane = threadIdx.x & 63;
    const float* src = S + (size_t)row*512 + lane*8;
    float4 a = *(const float4*)(src);
    float4 b = *(const float4*)(src + 4);
    float v[8] = {a.x,a.y,a.z,a.w,b.x,b.y,b.z,b.w};
    float m = v[0];
    #pragma unroll
    for (int j = 1; j < 8; j++) m = fmaxf(m, v[j]);
    #pragma unroll
    for (int off = 32; off > 0; off >>= 1) m = fmaxf(m, __shfl_xor(m, off));
    float s = 0.0f;
    #pragma unroll
    for (int j = 0; j < 8; j++) { v[j] = __expf(v[j]-m); s += v[j]; }
    #pragma unroll
    for (int off = 32; off > 0; off >>= 1) s += __shfl_xor(s, off);
    float inv = 1.0f/s;
    union { uint4 u; bf16 h[8]; } pk;
    #pragma unroll
    for (int j = 0; j < 8; j++) pk.h[j] = (bf16)(v[j]*inv);
    *(uint4*)(P + (size_t)row*512 + lane*8) = pk.u;
}

__global__ __launch_bounds__(256, 2)
void transpose_nt(const bf16* __restrict__ hs1, bf16* __restrict__ hs1T)
{
    __shared__ bf16 tile[64][72];
    int n = blockIdx.z, tX = blockIdx.x, fX = blockIdx.y;
    const bf16* src = hs1 + (size_t)n*512*512;
    for (int c = threadIdx.x; c < 512; c += 256) {
        int row = c >> 3, kch = c & 7;
        *(uint4*)(&tile[row][kch*8]) =
            *(const uint4*)(src + (size_t)(tX*64+row)*512 + fX*64 + kch*8);
    }
    __syncthreads();
    bf16* dst = hs1T + (size_t)n*512*512;
    for (int c = threadIdx.x; c < 512; c += 256) {
        int frow = c >> 3, tch = c & 7;
        bf16 tmp[8];
        #pragma unroll
        for (int j = 0; j < 8; j++) tmp[j] = tile[tch*8+j][frow];
        *(uint4*)(dst + (size_t)(fX*64+frow)*512 + tX*64 + tch*8) = *(uint4*)tmp;
    }
}

__global__ __launch_bounds__(256, 2)
void ctx_gemm(const bf16* __restrict__ P, const bf16* __restrict__ hs1T,
              bf16* __restrict__ ctx)
{
    __shared__ char smem[64*144*2];
    int n = blockIdx.z, tm = blockIdx.x, tn = blockIdx.y;
    const bf16* A0 = P    + (size_t)n*512*512 + (size_t)tm*64*512;
    const bf16* B0 = hs1T + (size_t)n*512*512 + (size_t)tn*64*512;
    floatx16 acc = gemm_loop(A0, B0, 512, 512, 512, 64, smem);
    int wave = threadIdx.x >> 6, lane = threadIdx.x & 63;
    int mi = wave & 1, ni = wave >> 1;
    #pragma unroll
    for (int r = 0; r < 16; r++) {
        int row = tm*64 + mi*32 + (r&3) + 8*(r>>2) + 4*(lane>>5);
        int col = tn*64 + ni*32 + (lane&31);
        ctx[((size_t)n*512 + row)*512 + col] = (bf16)acc[r];
    }
}

__global__ __launch_bounds__(256, 2)
void fc1_gemm(const bf16* __restrict__ ctx, const bf16* __restrict__ hs1,
              const bf16* __restrict__ wb, const float* __restrict__ b,
              float* __restrict__ outp)
{
    __shared__ char smem[64*144*2];
    const int tid = threadIdx.x;
    const int wave = tid >> 6, lane = tid & 63;
    const int mi = wave & 1, ni = wave >> 1;
    const int l31 = lane & 31, lh = lane >> 5;
    char* At = smem;
    char* Bt = smem + 64*144;
    const int m0 = blockIdx.x*64;
    floatx16 acc;
    #pragma unroll
    for (int r = 0; r < 16; r++) acc[r] = 0.0f;

    for (int kc = 0; kc < 1024; kc += 64) {
        const bf16* Asrc = (kc < 512) ? ctx : hs1;
        const int koff = kc & 511;
        __syncthreads();
        for (int c = tid; c < 1024; c += 256) {
            int which = c >> 9, idx = c & 511;
            int row = idx >> 3, kch = idx & 7;
            uint4 v;
            if (which == 0) {
                v = *(const uint4*)(Asrc + (size_t)(m0+row)*512 + koff + kch*8);
                *(uint4*)(At + row*144 + kch*16) = v;
            } else {
                if (row < 50) v = *(const uint4*)(wb + (size_t)row*1024 + kc + kch*8);
                else          v = make_uint4(0,0,0,0);
                *(uint4*)(Bt + row*144 + kch*16) = v;
            }
        }
        __syncthreads();
        #pragma unroll
        for (int ks = 0; ks < 4; ks++) {
            bf16x8 a = *(const bf16x8*)(At + (mi*32 + l31)*144 + ks*32 + lh*16);
            bf16x8 bb = *(const bf16x8*)(Bt + (ni*32 + l31)*144 + ks*32 + lh*16);
            acc = __builtin_amdgcn_mfma_f32_32x32x16_bf16(a, bb, acc, 0, 0, 0);
        }
    }
    #pragma unroll
    for (int r = 0; r < 16; r++) {
        int row = m0 + mi*32 + (r&3) + 8*(r>>2) + 4*lh;
        int col = ni*32 + l31;
        if (col < 50) {
            float v = acc[r] + b[col];
            outp[(size_t)row*50 + col] = fmaxf(v, 0.0f);
        }
    }
}

__global__ __launch_bounds__(256, 4)
void bn_stats(const float* __restrict__ fc1out, float* __restrict__ stats)
{
    __shared__ float sh[512];
    int c = blockIdx.x;
    float s = 0.0f, ss = 0.0f;
    for (int i = threadIdx.x; i < 32768; i += 256) {
        int n = i >> 9, q = i & 511;
        float x = fc1out[(size_t)n*25600 + c*512 + q];
        s += x; ss += x*x;
    }
    sh[threadIdx.x] = s; sh[256 + threadIdx.x] = ss;
    __syncthreads();
    for (int o = 128; o > 0; o >>= 1) {
        if (threadIdx.x < o) {
            sh[threadIdx.x] += sh[threadIdx.x + o];
            sh[256+threadIdx.x] += sh[256+threadIdx.x + o];
        }
        __syncthreads();
    }
    if (threadIdx.x == 0) {
        float mean = sh[0] / 32768.0f;
        float var  = sh[256] / 32768.0f - mean*mean;
        stats[c]      = mean;
        stats[64 + c] = rsqrtf(var + 1e-5f);
    }
}

__global__ __launch_bounds__(256, 4)
void tail_kernel(const float* __restrict__ fc1out, const float* __restrict__ stats,
                 const float* __restrict__ bng, const float* __restrict__ bnb,
                 const float* __restrict__ fc2w, const float* __restrict__ fc2b,
                 const float* __restrict__ fc3w, const float* __restrict__ fc3b,
                 const float* __restrict__ fc4w, const float* __restrict__ fc4b,
                 float* __restrict__ outp)
{
    __shared__ float W2[1250], W3[250], B2[25], B3[10], W4[20], B4[2];
    __shared__ float G[50], Bb[50], MU[50], IS[50];
    for (int i = threadIdx.x; i < 1250; i += 256) W2[i] = fc2w[i];
    for (int i = threadIdx.x; i < 250;  i += 256) W3[i] = fc3w[i];
    if (threadIdx.x < 25) B2[threadIdx.x] = fc2b[threadIdx.x];
    if (threadIdx.x < 20) W4[threadIdx.x] = fc4w[threadIdx.x];
    if (threadIdx.x < 10) B3[threadIdx.x] = fc3b[threadIdx.x];
    if (threadIdx.x < 2)  B4[threadIdx.x] = fc4b[threadIdx.x];
    if (threadIdx.x < 50) {
        G[threadIdx.x]  = bng[threadIdx.x];
        Bb[threadIdx.x] = bnb[threadIdx.x];
        MU[threadIdx.x] = stats[threadIdx.x];
        IS[threadIdx.x] = stats[64 + threadIdx.x];
    }
    __syncthreads();
    int m = blockIdx.x*256 + threadIdx.x;
    int t = m & 511;
    const float* src = fc1out + (size_t)m*50;
    float x[50];
    #pragma unroll
    for (int c = 0; c < 50; c++) {
        int j = (t*50 + c) >> 9;
        x[c] = (src[c] - MU[j])*IS[j]*G[j] + Bb[j];
    }
    float y2[25];
    #pragma unroll
    for (int o = 0; o < 25; o++) {
        float a = B2[o];
        for (int c = 0; c < 50; c++) a += x[c]*W2[o*50+c];
        y2[o] = fmaxf(a, 0.0f);
    }
    float y3[10];
    #pragma unroll
    for (int o = 0; o < 10; o++) {
        float a = B3[o];
        for (int c = 0; c < 25; c++) a += y2[c]*W3[o*25+c];
        y3[o] = fmaxf(a, 0.0f);
    }
    #pragma unroll
    for (int o = 0; o < 2; o++) {
        float a = B4[o];
        for (int c = 0; c < 10; c++) a += y3[c]*W4[o*10+c];
        outp[(size_t)m*2 + o] = a;
    }
}

extern "C" void kernel_launch(void* const* d_in, const int* in_sizes, int n_in,
                              void* d_out, int out_size, void* d_ws, size_t ws_size,
                              hipStream_t stream)
{
    const float* x       = (const float*)d_in[0];
    const float* wih_l0f = (const float*)d_in[1];
    const float* whh_l0f = (const float*)d_in[2];
    const float* b_l0f   = (const float*)d_in[3];
    const float* wih_l0b = (const float*)d_in[4];
    const float* whh_l0b = (const float*)d_in[5];
    const float* b_l0b   = (const float*)d_in[6];
    const float* wih_l1f = (const float*)d_in[7];
    const float* whh_l1f = (const float*)d_in[8];
    const float* b_l1f   = (const float*)d_in[9];
    const float* wih_l1b = (const float*)d_in[10];
    const float* whh_l1b = (const float*)d_in[11];
    const float* b_l1b   = (const float*)d_in[12];
    const float* fc1w    = (const float*)d_in[13];
    const float* fc1b    = (const float*)d_in[14];
    const float* bng     = (const float*)d_in[15];
    const float* bnb     = (const float*)d_in[16];
    const float* fc2w    = (const float*)d_in[17];
    const float* fc2b    = (const float*)d_in[18];
    const float* fc3w    = (const float*)d_in[19];
    const float* fc3b    = (const float*)d_in[20];
    const float* fc4w    = (const float*)d_in[21];
    const float* fc4b    = (const float*)d_in[22];

    char* ws = (char*)d_ws;
    float* stats  = (float*)ws;                        // 512 B
    bf16*  fc1wb  = (bf16*)(ws + 4096);                // 102400 B
    bf16*  hs0    = (bf16*)(ws + 131072);              // 32 MiB
    bf16*  hs1    = (bf16*)(ws + 33685504);            // 32 MiB
    float* xgA    = (float*)(ws + 67239936);           // 64 MiB
    float* xgB    = (float*)(ws + 134348800);          // 64 MiB
    bf16*  wb0f   = (bf16*)(ws + 201457664);           // 256 KiB
    bf16*  wb0b   = (bf16*)(ws + 201719808);           // 256 KiB
    bf16*  wb1f   = (bf16*)(ws + 201981952);           // 1 MiB
    bf16*  wb1b   = (bf16*)(ws + 203030528);           // 1 MiB
    bf16*  Wp0f   = (bf16*)(ws + 204079104);           // 512 KiB
    bf16*  Wp0b   = (bf16*)(ws + 204603392);           // 512 KiB
    bf16*  Wp1f   = (bf16*)(ws + 205127680);           // 512 KiB
    bf16*  Wp1b   = (bf16*)(ws + 205651968);           // 512 KiB
    float* cst    = (float*)(ws + 206176256);          // 128 KiB
    // post-rec overlays:
    bf16*  ctx    = (bf16*)(ws + 67239936);            // 32 MiB
    float* S      = (float*)(ws + 100794368);          // 64 MiB
    bf16*  P      = (bf16*)(ws + 167903232);           // 32 MiB
    float* fc1out = (float*)(ws + 201457664);          // 6.25 MiB
    bf16*  hs1T   = (bf16*)S;

    // ---- weight prep ----
    f2b_kernel<<<200, 256, 0, stream>>>(fc1w, fc1wb, 51200);
    f2b_kernel<<<512, 256, 0, stream>>>(wih_l0f, wb0f, 131072);
    f2b_kernel<<<512, 256, 0, stream>>>(wih_l0b, wb0b, 131072);
    f2b_kernel<<<2048, 256, 0, stream>>>(wih_l1f, wb1f, 524288);
    f2b_kernel<<<2048, 256, 0, stream>>>(wih_l1b, wb1b, 524288);
    pack_whh<<<128, 256, 0, stream>>>(whh_l0f, Wp0f);
    pack_whh<<<128, 256, 0, stream>>>(whh_l0b, Wp0b);
    pack_whh<<<128, 256, 0, stream>>>(whh_l1f, Wp1f);
    pack_whh<<<128, 256, 0, stream>>>(whh_l1b, Wp1b);

    constexpr int REC_LDS = 131072 + 2*8448;   // 147968 B
    constexpr int XG_LDS  = 2*18432;           // 36864 B
    hipFuncSetAttribute(reinterpret_cast<const void*>(&fused_kernel<128,true>),
                        hipFuncAttributeMaxDynamicSharedMemorySize, REC_LDS);
    hipFuncSetAttribute(reinterpret_cast<const void*>(&fused_kernel<512,false>),
                        hipFuncAttributeMaxDynamicSharedMemorySize, REC_LDS);

    // ---- layer 0: xg0, then rec(c) || xg(c+1) fused ----
    fused_kernel<128,true><<<2048, 512, XG_LDS, stream>>>(
        0, xgA, Wp0f, Wp0b, hs0, cst, 0,
        x, wb0f, wb0b, b_l0f, b_l0b, xgA, 0, 4096);
    fused_kernel<128,true><<<2056, 512, REC_LDS, stream>>>(
        8, xgA, Wp0f, Wp0b, hs0, cst, 0,
        x, wb0f, wb0b, b_l0f, b_l0b, xgB, 1, 4096);
    fused_kernel<128,true><<<2056, 512, REC_LDS, stream>>>(
        8, xgB, Wp0f, Wp0b, hs0, cst, 1,
        x, wb0f, wb0b, b_l0f, b_l0b, xgA, 2, 4096);
    fused_kernel<128,true><<<2056, 512, REC_LDS, stream>>>(
        8, xgA, Wp0f, Wp0b, hs0, cst, 2,
        x, wb0f, wb0b, b_l0f, b_l0b, xgB, 3, 4096);
    fused_kernel<128,true><<<8, 512, REC_LDS, stream>>>(
        8, xgB, Wp0f, Wp0b, hs0, cst, 3,
        x, wb0f, wb0b, b_l0f, b_l0b, xgA, 0, 0);

    // ---- layer 1 (input hs0 bf16) ----
    fused_kernel<512,false><<<2048, 512, XG_LDS, stream>>>(
        0, xgA, Wp1f, Wp1b, hs1, cst, 0,
        hs0, wb1f, wb1b, b_l1f, b_l1b, xgA, 0, 4096);
    fused_kernel<512,false><<<2056, 512, REC_LDS, stream>>>(
        8, xgA, Wp1f, Wp1b, hs1, cst, 0,
        hs0, wb1f, wb1b, b_l1f, b_l1b, xgB, 1, 4096);
    fused_kernel<512,false><<<2056, 512, REC_LDS, stream>>>(
        8, xgB, Wp1f, Wp1b, hs1, cst, 1,
        hs0, wb1f, wb1b, b_l1f, b_l1b, xgA, 2, 4096);
    fused_kernel<512,false><<<2056, 512, REC_LDS, stream>>>(
        8, xgA, Wp1f, Wp1b, hs1, cst, 2,
        hs0, wb1f, wb1b, b_l1f, b_l1b, xgB, 3, 4096);
    fused_kernel<512,false><<<8, 512, REC_LDS, stream>>>(
        8, xgB, Wp1f, Wp1b, hs1, cst, 3,
        hs0, wb1f, wb1b, b_l1f, b_l1b, xgA, 0, 0);

    // ---- attention + head ----
    dim3 g88(8, 8, 64);
    sgemm_scores<<<g88, 256, 0, stream>>>(hs1, S);
    softmax_rows<<<8192, 256, 0, stream>>>(S, P);
    transpose_nt<<<g88, 256, 0, stream>>>(hs1, hs1T);
    ctx_gemm<<<g88, 256, 0, stream>>>(P, hs1T, ctx);
    fc1_gemm<<<512, 256, 0, stream>>>(ctx, hs1, fc1wb, fc1b, fc1out);
    bn_stats<<<50, 256, 0, stream>>>(fc1out, stats);
    tail_kernel<<<128, 256, 0, stream>>>(fc1out, stats, bng, bnb, fc2w, fc2b,
                                         fc3w, fc3b, fc4w, fc4b, (float*)d_out);
    (void)in_sizes; (void)n_in; (void)out_size; (void)ws_size;
}

// Round 3
// 3485.323 us; speedup vs baseline: 3.2680x; 1.6244x over previous
//
#include <hip/hip_runtime.h>
#include <hip/hip_bf16.h>

typedef __bf16 bf16;
typedef __bf16 bf16x8 __attribute__((ext_vector_type(8)));
typedef float floatx4 __attribute__((ext_vector_type(4)));
typedef float floatx16 __attribute__((ext_vector_type(16)));

#define TSEQ 512
#define MFMA16 __builtin_amdgcn_mfma_f32_16x16x32_bf16

__device__ __forceinline__ float sigm(float x){ return 1.0f/(1.0f + __expf(-x)); }
__device__ __forceinline__ float tanh_fast(float x){
    float e = __expf(2.0f*x);
    return 1.0f - 2.0f/(e + 1.0f);   // correct limits at +-inf
}

// fp32 -> bf16 converter
__global__ __launch_bounds__(256, 4)
void f2b_kernel(const float* __restrict__ in, bf16* __restrict__ out, int n)
{
    int i = blockIdx.x*256 + threadIdx.x;
    if (i < n) out[i] = (bf16)in[i];
}

// ---------------------------------------------------------------------------
// Pack Whh (1024 x 256 fp32) into MFMA-16x16x32 B-frag-major bf16 layout:
// Wp[ntile 0..63][kstep 0..7][lane 0..63][e 0..7], value =
//   Whh[gatecol = ntile*16 + (lane&15)][k = kstep*32 + (lane>>4)*8 + e]
// ---------------------------------------------------------------------------
__global__ __launch_bounds__(256, 4)
void pack_whh(const float* __restrict__ whh, bf16* __restrict__ wp)
{
    int idx = blockIdx.x*256 + threadIdx.x;
    if (idx >= 32768) return;
    int lane = idx & 63, ks = (idx >> 6) & 7, nt = idx >> 9;
    int row = nt*16 + (lane & 15);
    int k0  = ks*32 + (lane >> 4)*8;
    const float* src = whh + (size_t)row*256 + k0;
    bf16x8 v;
    #pragma unroll
    for (int e = 0; e < 8; e++) v[e] = (bf16)src[e];
    ((bf16x8*)wp)[idx] = v;
}

// ---------------------------------------------------------------------------
// xg = x @ Wih^T + bias for one 256-step chunk, both dirs (blockIdx.z).
// Output natural layout: xg[dir][seq 0..63][sloc 0..255][1024] fp32,
// sloc = step index (fwd: t = chunk*256+sloc; bwd: t = 511-(chunk*256+sloc)).
// Grid (256, 16, 2): bx = seq*4 + tblk, by = coltile, bz = dir. 256 thr.
// ---------------------------------------------------------------------------
template<int DIN, bool XF32>
__global__ __launch_bounds__(256, 2)
void xg_gemm(const void* __restrict__ xin,
             const bf16* __restrict__ wbf, const bf16* __restrict__ wbb,
             const float* __restrict__ bf_, const float* __restrict__ bb_,
             float* __restrict__ xg, int chunk)
{
    __shared__ char smem[64*144*2];
    const int tid = threadIdx.x;
    const int wv = tid >> 6, ln = tid & 63;
    const int mi = wv & 1, ni = wv >> 1;
    const int l31 = ln & 31, lh = ln >> 5;
    char* At = smem;
    char* Bt = smem + 64*144;

    const int d   = blockIdx.z;
    const int seq = blockIdx.x >> 2;
    const int tb  = blockIdx.x & 3;
    const int n0  = blockIdx.y * 64;
    const bf16*  wb   = d ? wbb : wbf;
    const float* bias = d ? bb_ : bf_;
    const int sl0 = tb*64;
    const int t0  = d ? (511 - (chunk*256 + sl0)) : (chunk*256 + sl0);
    const int stp = d ? -1 : 1;

    floatx16 acc;
    #pragma unroll
    for (int r = 0; r < 16; r++) acc[r] = 0.0f;

    for (int kc = 0; kc < DIN; kc += 64) {
        __syncthreads();
        for (int c = tid; c < 1024; c += 256) {
            const int which = c >> 9, idx = c & 511;
            const int row = idx >> 3, k8 = idx & 7;
            if (which == 0) {
                const int trow = t0 + row*stp;
                if constexpr (XF32) {
                    const float* src = (const float*)xin
                        + ((size_t)seq*TSEQ + trow)*DIN + kc + k8*8;
                    const float4 lo = *(const float4*)src;
                    const float4 hi = *(const float4*)(src+4);
                    bf16 tmp[8] = {(bf16)lo.x,(bf16)lo.y,(bf16)lo.z,(bf16)lo.w,
                                   (bf16)hi.x,(bf16)hi.y,(bf16)hi.z,(bf16)hi.w};
                    *(uint4*)(At + row*144 + k8*16) = *(uint4*)tmp;
                } else {
                    const bf16* src = (const bf16*)xin
                        + ((size_t)seq*TSEQ + trow)*DIN + kc + k8*8;
                    *(uint4*)(At + row*144 + k8*16) = *(const uint4*)src;
                }
            } else {
                *(uint4*)(Bt + row*144 + k8*16) =
                    *(const uint4*)(wb + (size_t)(n0+row)*DIN + kc + k8*8);
            }
        }
        __syncthreads();
        #pragma unroll
        for (int ks = 0; ks < 4; ks++) {
            bf16x8 a = *(const bf16x8*)(At + (mi*32 + l31)*144 + ks*32 + lh*16);
            bf16x8 b = *(const bf16x8*)(Bt + (ni*32 + l31)*144 + ks*32 + lh*16);
            acc = __builtin_amdgcn_mfma_f32_32x32x16_bf16(a, b, acc, 0, 0, 0);
        }
    }
    const int col = n0 + ni*32 + l31;
    const float bv = bias[col];
    #pragma unroll
    for (int r = 0; r < 16; r++) {
        const int rowl = mi*32 + (r&3) + 8*(r>>2) + 4*lh;
        const int sloc = sl0 + rowl;
        xg[((size_t)(d*64 + seq)*256 + sloc)*1024 + col] = acc[r] + bv;
    }
}

// ---------------------------------------------------------------------------
// Batch-split recurrence, LDS-BW-optimized. 16 blocks = 2 dir x 8 groups of
// 8 seqs; 512 thr (8 waves, 2/SIMD -> 256 reg budget/wave).
// A rows 8..15 alias rows 0..7 (free duplicate) -> all lanes own valid cells
// via cndmask select; no divergence, no shuffles.
// Per step per wave: 8x(1 A-read + 2 Wlds reads + 8 MFMA) single-pass.
// Weight tiers per wave (j = gate*2+u, nt = gate*16 + 2w + u):
//   j0,1 (i): LDS (nt 0..15, 128 KiB)     j2..6 (f,g,o-even): VGPR (160 regs)
//   j7 (o-odd): streamed from L2 (8 KB/wave/step), LICM-guarded
// xg is the MFMA C-in (fp32, natural layout, bias included), gathered with
// imm-offset loads, refilled per-gate right after last use.
// ---------------------------------------------------------------------------
__global__ __launch_bounds__(512, 1)
void rec_kernel(const float* __restrict__ xg,
                const bf16* __restrict__ WpF, const bf16* __restrict__ WpB,
                bf16* __restrict__ hsout, float* __restrict__ cst, int chunk)
{
    extern __shared__ char smem[];
    bf16x8* Wlds = (bf16x8*)smem;            // 8192 frags = 128 KiB
    char* hb0 = smem + 131072;               // 8 rows x 528 B
    char* hb1 = hb0 + 4224;

    const int tid = threadIdx.x;
    const int w = tid >> 6, l = tid & 63;
    const int l15 = l & 15, lq = l >> 4;
    const int blk = blockIdx.x;
    const int d = blk >> 3, bg = blk & 7;
    const bf16x8* Wp = (const bf16x8*)(d ? WpB : WpF);

    // LDS tier: ntiles 0..15 (i-gate)
    for (int i = tid; i < 8192; i += 512) Wlds[i] = Wp[i];

    // VGPR tier: j=2..6
    bf16x8 WV0[8], WV1[8], WV2[8], WV3[8], WV4[8];
    #pragma unroll
    for (int ks = 0; ks < 8; ks++) {
        WV0[ks] = Wp[((16+2*w)*8+ks)*64 + l];
        WV1[ks] = Wp[((17+2*w)*8+ks)*64 + l];
        WV2[ks] = Wp[((32+2*w)*8+ks)*64 + l];
        WV3[ks] = Wp[((33+2*w)*8+ks)*64 + l];
        WV4[ks] = Wp[((48+2*w)*8+ks)*64 + l];
    }
    // streamed tier: j=7 (nt 49+2w)
    const int sbBase = ((49+2*w)*8)*64 + l;
    bf16x8 SB[8];
    #pragma unroll
    for (int ks = 0; ks < 8; ks++) SB[ks] = Wp[sbBase + ks*64];

    // h buffers (8 rows only; MFMA A rows 8..15 alias via l15&7)
    if (chunk == 0) {
        uint4 z = make_uint4(0,0,0,0);
        for (int i = tid; i < 528; i += 512) ((uint4*)hb0)[i] = z; // covers hb0+hb1
    } else {
        if (tid < 256) {
            const int tprev = d ? (512 - chunk*256) : (chunk*256 - 1);
            const int sq = tid >> 5, col = (tid & 31) * 8;
            uint4 v = *(const uint4*)(hsout
                + ((size_t)(bg*8+sq)*TSEQ + tprev)*512 + d*256 + col);
            *(uint4*)(hb0 + sq*528 + col*2) = v;
        }
    }

    // c-state: cells (u, rr), seq = (lq&1)*4 + (lq>>1)*2 + rr, col=(2w+u)*16+l15
    float cs[2][2];
    if (chunk == 0) {
        cs[0][0]=cs[0][1]=cs[1][0]=cs[1][1]=0.0f;
    } else {
        float4 cv = ((const float4*)cst)[blk*512 + tid];
        cs[0][0]=cv.x; cs[0][1]=cv.y; cs[1][0]=cv.z; cs[1][1]=cv.w;
    }

    // xg gather offsets: slot (j,r) -> seq8=(lq*4+r)&7, col=(j>>1)*256+(j&1)*16 + 2w*16+l15
    const float* xgb = xg + (size_t)(d*64 + bg*8)*256*1024;
    int vo[4];
    #pragma unroll
    for (int r = 0; r < 4; r++)
        vo[r] = ((lq*4 + r) & 7)*(256*1024) + (2*w)*16 + l15;

    // prologue C-in = xg(sloc=0)
    floatx4 acc[8];
    #pragma unroll
    for (int j = 0; j < 8; j++) {
        const int joff = (j>>1)*256 + (j&1)*16;
        #pragma unroll
        for (int r = 0; r < 4; r++) acc[j][r] = xgb[vo[r] + joff];
    }

    __syncthreads();

    const int aoff = (l15 & 7)*528 + lq*16;
    const int wi0 = ((2*w)*8)*64 + l;
    const int wi1 = ((2*w+1)*8)*64 + l;
    const bool hi = (lq >= 2);
    const int sA = (lq & 1)*4 + (lq >> 1)*2;

    for (int sl = 0; sl < 256; ++sl) {
        const int s = chunk*256 + sl;
        const int t = d ? (511 - s) : s;
        const char* hr = (s & 1) ? hb1 : hb0;
        char* hw = (s & 1) ? hb0 : hb1;

        int zx;
        asm volatile("s_mov_b32 %0, 0" : "=s"(zx));   // defeat LICM on SB refill

        // ---- single-pass MFMA: gates = xg + h_prev @ Whh^T ----
        bf16x8 Ac = *(const bf16x8*)(hr + aoff);
        #pragma unroll
        for (int ks = 0; ks < 8; ks++) {
            bf16x8 An = Ac;
            if (ks < 7) An = *(const bf16x8*)(hr + aoff + (ks+1)*64);
            acc[0] = MFMA16(Ac, Wlds[wi0 + ks*64], acc[0], 0,0,0);
            acc[1] = MFMA16(Ac, Wlds[wi1 + ks*64], acc[1], 0,0,0);
            acc[2] = MFMA16(Ac, WV0[ks], acc[2], 0,0,0);
            acc[3] = MFMA16(Ac, WV1[ks], acc[3], 0,0,0);
            acc[4] = MFMA16(Ac, WV2[ks], acc[4], 0,0,0);
            acc[5] = MFMA16(Ac, WV3[ks], acc[5], 0,0,0);
            acc[6] = MFMA16(Ac, WV4[ks], acc[6], 0,0,0);
            acc[7] = MFMA16(Ac, SB[ks], acc[7], 0,0,0);
            Ac = An;
        }
        // refill streamed tier for next step (full-step latency cover)
        #pragma unroll
        for (int ks = 0; ks < 8; ks++) SB[ks] = Wp[sbBase + ks*64 + zx];

        // advance xg offsets to sloc+1
        #pragma unroll
        for (int r = 0; r < 4; r++) vo[r] += 1024;

        // ---- gate math: 4 cells/thread, all lanes valid via cndmask ----
        float hvv[2][2];
        #pragma unroll
        for (int u = 0; u < 2; u++) {
            #pragma unroll
            for (int rr = 0; rr < 2; rr++) {
                const float gI = hi ? acc[0+u][2+rr] : acc[0+u][rr];
                const float gF = hi ? acc[2+u][2+rr] : acc[2+u][rr];
                const float gG = hi ? acc[4+u][2+rr] : acc[4+u][rr];
                const float gO = hi ? acc[6+u][2+rr] : acc[6+u][rr];
                const float cn = sigm(gF)*cs[u][rr] + sigm(gI)*tanh_fast(gG);
                cs[u][rr] = cn;
                hvv[u][rr] = sigm(gO)*tanh_fast(cn);
            }
            // refill C-in for this u's gates (acc[j] dead after selects above)
            if (sl < 255) {
                #pragma unroll
                for (int g = 0; g < 4; g++) {
                    const int j = g*2 + u;
                    const int joff = g*256 + u*16;
                    #pragma unroll
                    for (int r = 0; r < 4; r++)
                        acc[j][r] = xgb[vo[r] + joff];
                }
            }
        }

        // ---- h stores: LDS (next step A) + global ----
        #pragma unroll
        for (int u = 0; u < 2; u++) {
            const int col = (2*w+u)*16 + l15;
            #pragma unroll
            for (int rr = 0; rr < 2; rr++) {
                const bf16 hb_ = (bf16)hvv[u][rr];
                *(bf16*)(hw + (sA+rr)*528 + col*2) = hb_;
                hsout[((size_t)(bg*8 + sA + rr)*TSEQ + t)*512 + d*256 + col] = hb_;
            }
        }
        __syncthreads();
    }

    ((float4*)cst)[blk*512 + tid] =
        make_float4(cs[0][0], cs[0][1], cs[1][0], cs[1][1]);
}

// ---------------------------------------------------------------------------
// Shared 64x64 bf16 GEMM main loop (attention chain) — unchanged.
// ---------------------------------------------------------------------------
__device__ __forceinline__ floatx16 gemm_loop(const bf16* __restrict__ A0,
                                              const bf16* __restrict__ Bt0,
                                              int lda, int ldb, int K, int brows,
                                              char* smem)
{
    const int tid = threadIdx.x;
    const int wave = tid >> 6, lane = tid & 63;
    const int mi = wave & 1, ni = wave >> 1;
    const int l31 = lane & 31, lh = lane >> 5;
    char* At = smem;
    char* Bt = smem + 64*144;
    floatx16 acc;
    #pragma unroll
    for (int r = 0; r < 16; r++) acc[r] = 0.0f;

    for (int kc = 0; kc < K; kc += 64) {
        __syncthreads();
        for (int c = tid; c < 1024; c += 256) {
            int which = c >> 9;
            int idx = c & 511;
            int row = idx >> 3, kch = idx & 7;
            uint4 v;
            if (which == 0) {
                v = *(const uint4*)(A0 + (size_t)row*lda + kc + kch*8);
                *(uint4*)(At + row*144 + kch*16) = v;
            } else {
                if (row < brows) v = *(const uint4*)(Bt0 + (size_t)row*ldb + kc + kch*8);
                else             v = make_uint4(0,0,0,0);
                *(uint4*)(Bt + row*144 + kch*16) = v;
            }
        }
        __syncthreads();
        #pragma unroll
        for (int ks = 0; ks < 4; ks++) {
            bf16x8 a = *(const bf16x8*)(At + (mi*32 + l31)*144 + ks*32 + lh*16);
            bf16x8 b = *(const bf16x8*)(Bt + (ni*32 + l31)*144 + ks*32 + lh*16);
            acc = __builtin_amdgcn_mfma_f32_32x32x16_bf16(a, b, acc, 0, 0, 0);
        }
    }
    return acc;
}

__global__ __launch_bounds__(256, 2)
void sgemm_scores(const bf16* __restrict__ hs1, float* __restrict__ S)
{
    __shared__ char smem[64*144*2];
    int n = blockIdx.z, tm = blockIdx.x, tn = blockIdx.y;
    const bf16* base = hs1 + (size_t)n*512*512;
    floatx16 acc = gemm_loop(base + (size_t)tm*64*512, base + (size_t)tn*64*512,
                             512, 512, 512, 64, smem);
    int wave = threadIdx.x >> 6, lane = threadIdx.x & 63;
    int mi = wave & 1, ni = wave >> 1;
    #pragma unroll
    for (int r = 0; r < 16; r++) {
        int row = tm*64 + mi*32 + (r&3) + 8*(r>>2) + 4*(lane>>5);
        int col = tn*64 + ni*32 + (lane&31);
        S[(size_t)n*512*512 + (size_t)row*512 + col] = acc[r];
    }
}

__global__ __launch_bounds__(256, 4)
void softmax_rows(const float* __restrict__ S, bf16* __restrict__ P)
{
    int row = blockIdx.x*4 + (threadIdx.x >> 6);
    int lane = threadIdx.x & 63;
    const float* src = S + (size_t)row*512 + lane*8;
    float4 a = *(const float4*)(src);
    float4 b = *(const float4*)(src + 4);
    float v[8] = {a.x,a.y,a.z,a.w,b.x,b.y,b.z,b.w};
    float m = v[0];
    #pragma unroll
    for (int j = 1; j < 8; j++) m = fmaxf(m, v[j]);
    #pragma unroll
    for (int off = 32; off > 0; off >>= 1) m = fmaxf(m, __shfl_xor(m, off));
    float s = 0.0f;
    #pragma unroll
    for (int j = 0; j < 8; j++) { v[j] = __expf(v[j]-m); s += v[j]; }
    #pragma unroll
    for (int off = 32; off > 0; off >>= 1) s += __shfl_xor(s, off);
    float inv = 1.0f/s;
    union { uint4 u; bf16 h[8]; } pk;
    #pragma unroll
    for (int j = 0; j < 8; j++) pk.h[j] = (bf16)(v[j]*inv);
    *(uint4*)(P + (size_t)row*512 + lane*8) = pk.u;
}

__global__ __launch_bounds__(256, 2)
void transpose_nt(const bf16* __restrict__ hs1, bf16* __restrict__ hs1T)
{
    __shared__ bf16 tile[64][72];
    int n = blockIdx.z, tX = blockIdx.x, fX = blockIdx.y;
    const bf16* src = hs1 + (size_t)n*512*512;
    for (int c = threadIdx.x; c < 512; c += 256) {
        int row = c >> 3, kch = c & 7;
        *(uint4*)(&tile[row][kch*8]) =
            *(const uint4*)(src + (size_t)(tX*64+row)*512 + fX*64 + kch*8);
    }
    __syncthreads();
    bf16* dst = hs1T + (size_t)n*512*512;
    for (int c = threadIdx.x; c < 512; c += 256) {
        int frow = c >> 3, tch = c & 7;
        bf16 tmp[8];
        #pragma unroll
        for (int j = 0; j < 8; j++) tmp[j] = tile[tch*8+j][frow];
        *(uint4*)(dst + (size_t)(fX*64+frow)*512 + tX*64 + tch*8) = *(uint4*)tmp;
    }
}

__global__ __launch_bounds__(256, 2)
void ctx_gemm(const bf16* __restrict__ P, const bf16* __restrict__ hs1T,
              bf16* __restrict__ ctx)
{
    __shared__ char smem[64*144*2];
    int n = blockIdx.z, tm = blockIdx.x, tn = blockIdx.y;
    const bf16* A0 = P    + (size_t)n*512*512 + (size_t)tm*64*512;
    const bf16* B0 = hs1T + (size_t)n*512*512 + (size_t)tn*64*512;
    floatx16 acc = gemm_loop(A0, B0, 512, 512, 512, 64, smem);
    int wave = threadIdx.x >> 6, lane = threadIdx.x & 63;
    int mi = wave & 1, ni = wave >> 1;
    #pragma unroll
    for (int r = 0; r < 16; r++) {
        int row = tm*64 + mi*32 + (r&3) + 8*(r>>2) + 4*(lane>>5);
        int col = tn*64 + ni*32 + (lane&31);
        ctx[((size_t)n*512 + row)*512 + col] = (bf16)acc[r];
    }
}

__global__ __launch_bounds__(256, 2)
void fc1_gemm(const bf16* __restrict__ ctx, const bf16* __restrict__ hs1,
              const bf16* __restrict__ wb, const float* __restrict__ b,
              float* __restrict__ outp)
{
    __shared__ char smem[64*144*2];
    const int tid = threadIdx.x;
    const int wave = tid >> 6, lane = tid & 63;
    const int mi = wave & 1, ni = wave >> 1;
    const int l31 = lane & 31, lh = lane >> 5;
    char* At = smem;
    char* Bt = smem + 64*144;
    const int m0 = blockIdx.x*64;
    floatx16 acc;
    #pragma unroll
    for (int r = 0; r < 16; r++) acc[r] = 0.0f;

    for (int kc = 0; kc < 1024; kc += 64) {
        const bf16* Asrc = (kc < 512) ? ctx : hs1;
        const int koff = kc & 511;
        __syncthreads();
        for (int c = tid; c < 1024; c += 256) {
            int which = c >> 9, idx = c & 511;
            int row = idx >> 3, kch = idx & 7;
            uint4 v;
            if (which == 0) {
                v = *(const uint4*)(Asrc + (size_t)(m0+row)*512 + koff + kch*8);
                *(uint4*)(At + row*144 + kch*16) = v;
            } else {
                if (row < 50) v = *(const uint4*)(wb + (size_t)row*1024 + kc + kch*8);
                else          v = make_uint4(0,0,0,0);
                *(uint4*)(Bt + row*144 + kch*16) = v;
            }
        }
        __syncthreads();
        #pragma unroll
        for (int ks = 0; ks < 4; ks++) {
            bf16x8 a = *(const bf16x8*)(At + (mi*32 + l31)*144 + ks*32 + lh*16);
            bf16x8 bb = *(const bf16x8*)(Bt + (ni*32 + l31)*144 + ks*32 + lh*16);
            acc = __builtin_amdgcn_mfma_f32_32x32x16_bf16(a, bb, acc, 0, 0, 0);
        }
    }
    #pragma unroll
    for (int r = 0; r < 16; r++) {
        int row = m0 + mi*32 + (r&3) + 8*(r>>2) + 4*lh;
        int col = ni*32 + l31;
        if (col < 50) {
            float v = acc[r] + b[col];
            outp[(size_t)row*50 + col] = fmaxf(v, 0.0f);
        }
    }
}

__global__ __launch_bounds__(256, 4)
void bn_stats(const float* __restrict__ fc1out, float* __restrict__ stats)
{
    __shared__ float sh[512];
    int c = blockIdx.x;
    float s = 0.0f, ss = 0.0f;
    for (int i = threadIdx.x; i < 32768; i += 256) {
        int n = i >> 9, q = i & 511;
        float x = fc1out[(size_t)n*25600 + c*512 + q];
        s += x; ss += x*x;
    }
    sh[threadIdx.x] = s; sh[256 + threadIdx.x] = ss;
    __syncthreads();
    for (int o = 128; o > 0; o >>= 1) {
        if (threadIdx.x < o) {
            sh[threadIdx.x] += sh[threadIdx.x + o];
            sh[256+threadIdx.x] += sh[256+threadIdx.x + o];
        }
        __syncthreads();
    }
    if (threadIdx.x == 0) {
        float mean = sh[0] / 32768.0f;
        float var  = sh[256] / 32768.0f - mean*mean;
        stats[c]      = mean;
        stats[64 + c] = rsqrtf(var + 1e-5f);
    }
}

__global__ __launch_bounds__(256, 4)
void tail_kernel(const float* __restrict__ fc1out, const float* __restrict__ stats,
                 const float* __restrict__ bng, const float* __restrict__ bnb,
                 const float* __restrict__ fc2w, const float* __restrict__ fc2b,
                 const float* __restrict__ fc3w, const float* __restrict__ fc3b,
                 const float* __restrict__ fc4w, const float* __restrict__ fc4b,
                 float* __restrict__ outp)
{
    __shared__ float W2[1250], W3[250], B2[25], B3[10], W4[20], B4[2];
    __shared__ float G[50], Bb[50], MU[50], IS[50];
    for (int i = threadIdx.x; i < 1250; i += 256) W2[i] = fc2w[i];
    for (int i = threadIdx.x; i < 250;  i += 256) W3[i] = fc3w[i];
    if (threadIdx.x < 25) B2[threadIdx.x] = fc2b[threadIdx.x];
    if (threadIdx.x < 20) W4[threadIdx.x] = fc4w[threadIdx.x];
    if (threadIdx.x < 10) B3[threadIdx.x] = fc3b[threadIdx.x];
    if (threadIdx.x < 2)  B4[threadIdx.x] = fc4b[threadIdx.x];
    if (threadIdx.x < 50) {
        G[threadIdx.x]  = bng[threadIdx.x];
        Bb[threadIdx.x] = bnb[threadIdx.x];
        MU[threadIdx.x] = stats[threadIdx.x];
        IS[threadIdx.x] = stats[64 + threadIdx.x];
    }
    __syncthreads();
    int m = blockIdx.x*256 + threadIdx.x;
    int t = m & 511;
    const float* src = fc1out + (size_t)m*50;
    float x[50];
    #pragma unroll
    for (int c = 0; c < 50; c++) {
        int j = (t*50 + c) >> 9;
        x[c] = (src[c] - MU[j])*IS[j]*G[j] + Bb[j];
    }
    float y2[25];
    #pragma unroll
    for (int o = 0; o < 25; o++) {
        float a = B2[o];
        for (int c = 0; c < 50; c++) a += x[c]*W2[o*50+c];
        y2[o] = fmaxf(a, 0.0f);
    }
    float y3[10];
    #pragma unroll
    for (int o = 0; o < 10; o++) {
        float a = B3[o];
        for (int c = 0; c < 25; c++) a += y2[c]*W3[o*25+c];
        y3[o] = fmaxf(a, 0.0f);
    }
    #pragma unroll
    for (int o = 0; o < 2; o++) {
        float a = B4[o];
        for (int c = 0; c < 10; c++) a += y3[c]*W4[o*10+c];
        outp[(size_t)m*2 + o] = a;
    }
}

extern "C" void kernel_launch(void* const* d_in, const int* in_sizes, int n_in,
                              void* d_out, int out_size, void* d_ws, size_t ws_size,
                              hipStream_t stream)
{
    const float* x       = (const float*)d_in[0];
    const float* wih_l0f = (const float*)d_in[1];
    const float* whh_l0f = (const float*)d_in[2];
    const float* b_l0f   = (const float*)d_in[3];
    const float* wih_l0b = (const float*)d_in[4];
    const float* whh_l0b = (const float*)d_in[5];
    const float* b_l0b   = (const float*)d_in[6];
    const float* wih_l1f = (const float*)d_in[7];
    const float* whh_l1f = (const float*)d_in[8];
    const float* b_l1f   = (const float*)d_in[9];
    const float* wih_l1b = (const float*)d_in[10];
    const float* whh_l1b = (const float*)d_in[11];
    const float* b_l1b   = (const float*)d_in[12];
    const float* fc1w    = (const float*)d_in[13];
    const float* fc1b    = (const float*)d_in[14];
    const float* bng     = (const float*)d_in[15];
    const float* bnb     = (const float*)d_in[16];
    const float* fc2w    = (const float*)d_in[17];
    const float* fc2b    = (const float*)d_in[18];
    const float* fc3w    = (const float*)d_in[19];
    const float* fc3b    = (const float*)d_in[20];
    const float* fc4w    = (const float*)d_in[21];
    const float* fc4b    = (const float*)d_in[22];

    // ---- workspace layout (ends at 208,011,264 B, same as proven) ----
    char* ws = (char*)d_ws;
    float* stats  = (float*)ws;                        // 512 B
    bf16*  fc1wb  = (bf16*)(ws + 4096);                // 102400 B
    bf16*  hs0    = (bf16*)(ws + 131072);              // 32 MiB
    bf16*  hs1    = (bf16*)(ws + 33685504);            // 32 MiB
    float* xg     = (float*)(ws + 67239936);           // 128 MiB (one chunk, reused)
    bf16*  wb0f   = (bf16*)(ws + 201457664);           // 256 KiB
    bf16*  wb0b   = (bf16*)(ws + 201719808);           // 256 KiB
    bf16*  wb1f   = (bf16*)(ws + 201981952);           // 1 MiB
    bf16*  wb1b   = (bf16*)(ws + 203030528);           // 1 MiB
    bf16*  Wp0f   = (bf16*)(ws + 204079104);           // 512 KiB
    bf16*  Wp0b   = (bf16*)(ws + 204603392);           // 512 KiB
    bf16*  Wp1f   = (bf16*)(ws + 205127680);           // 512 KiB
    bf16*  Wp1b   = (bf16*)(ws + 205651968);           // 512 KiB
    float* cst    = (float*)(ws + 206176256);          // 128 KiB
    // post-rec overlays (xg / weight packs dead by then):
    bf16*  ctx    = (bf16*)(ws + 67239936);            // 32 MiB
    float* S      = (float*)(ws + 100794368);          // 64 MiB
    bf16*  P      = (bf16*)(ws + 167903232);           // 32 MiB
    float* fc1out = (float*)(ws + 201457664);          // 6.25 MiB
    bf16*  hs1T   = (bf16*)S;

    // ---- weight prep ----
    f2b_kernel<<<200, 256, 0, stream>>>(fc1w, fc1wb, 51200);
    f2b_kernel<<<512, 256, 0, stream>>>(wih_l0f, wb0f, 131072);
    f2b_kernel<<<512, 256, 0, stream>>>(wih_l0b, wb0b, 131072);
    f2b_kernel<<<2048, 256, 0, stream>>>(wih_l1f, wb1f, 524288);
    f2b_kernel<<<2048, 256, 0, stream>>>(wih_l1b, wb1b, 524288);
    pack_whh<<<128, 256, 0, stream>>>(whh_l0f, Wp0f);
    pack_whh<<<128, 256, 0, stream>>>(whh_l0b, Wp0b);
    pack_whh<<<128, 256, 0, stream>>>(whh_l1f, Wp1f);
    pack_whh<<<128, 256, 0, stream>>>(whh_l1b, Wp1b);

    constexpr int REC_LDS = 131072 + 2*4224;   // 139,520 B
    hipFuncSetAttribute(reinterpret_cast<const void*>(&rec_kernel),
                        hipFuncAttributeMaxDynamicSharedMemorySize, REC_LDS);

    dim3 gxg(256, 16, 2);
    // ---- layer 0 ----
    xg_gemm<128, true><<<gxg, 256, 0, stream>>>(x, wb0f, wb0b, b_l0f, b_l0b, xg, 0);
    rec_kernel<<<16, 512, REC_LDS, stream>>>(xg, Wp0f, Wp0b, hs0, cst, 0);
    xg_gemm<128, true><<<gxg, 256, 0, stream>>>(x, wb0f, wb0b, b_l0f, b_l0b, xg, 1);
    rec_kernel<<<16, 512, REC_LDS, stream>>>(xg, Wp0f, Wp0b, hs0, cst, 1);
    // ---- layer 1 ----
    xg_gemm<512, false><<<gxg, 256, 0, stream>>>(hs0, wb1f, wb1b, b_l1f, b_l1b, xg, 0);
    rec_kernel<<<16, 512, REC_LDS, stream>>>(xg, Wp1f, Wp1b, hs1, cst, 0);
    xg_gemm<512, false><<<gxg, 256, 0, stream>>>(hs0, wb1f, wb1b, b_l1f, b_l1b, xg, 1);
    rec_kernel<<<16, 512, REC_LDS, stream>>>(xg, Wp1f, Wp1b, hs1, cst, 1);

    // ---- attention + head ----
    dim3 g88(8, 8, 64);
    sgemm_scores<<<g88, 256, 0, stream>>>(hs1, S);
    softmax_rows<<<8192, 256, 0, stream>>>(S, P);
    transpose_nt<<<g88, 256, 0, stream>>>(hs1, hs1T);
    ctx_gemm<<<g88, 256, 0, stream>>>(P, hs1T, ctx);
    fc1_gemm<<<512, 256, 0, stream>>>(ctx, hs1, fc1wb, fc1b, fc1out);
    bn_stats<<<50, 256, 0, stream>>>(fc1out, stats);
    tail_kernel<<<128, 256, 0, stream>>>(fc1out, stats, bng, bnb, fc2w, fc2b,
                                         fc3w, fc3b, fc4w, fc4b, (float*)d_out);
    (void)in_sizes; (void)n_in; (void)out_size; (void)ws_size;
}